// Round 2
// baseline (999.474 us; speedup 1.0000x reference)
//
#include <hip/hip_runtime.h>
#include <math.h>

// Problem constants
#define BB 4
#define TT 32
#define HH 160
#define WW 320
#define NF 8
#define FPF 8
#define SDIM 8
#define UU 64
#define SS 72            // NF*FPF + SDIM
#define UNFOLDS 6

__device__ __forceinline__ float fast_sigmoid(float x) {
    float e = exp2f(-1.44269504f * x);
    return __builtin_amdgcn_rcpf(1.0f + e);
}

// ---------------- weight transpose: [oc][ic][5][5] -> [ic*25+j][oc] ----------------
__global__ void transpose_w_kernel(const float* __restrict__ w, float* __restrict__ wt,
                                   int OC, int IC) {
    int i = blockIdx.x * 256 + threadIdx.x;
    int total = OC * IC * 25;
    if (i >= total) return;
    int oc = i % OC;
    int rest = i / OC;
    int j = rest % 25;
    int ic = rest / 25;
    wt[i] = w[(oc * IC + ic) * 25 + j];
}

// ---------------- direct 5x5 stride-2 pad-2 conv + relu, NOX outputs/thread ----------------
// one thread computes all OC channels for NOX adjacent (n, oy, ox0..ox0+NOX-1)
// input row segment in registers; weights as float4, reused across NOX columns.
template <int IC, int OC, int NOX>
__global__ __launch_bounds__(256) void conv5x5_multi(
    const float* __restrict__ in, const float* __restrict__ wt,
    const float* __restrict__ bias, float* __restrict__ out,
    int N, int IH, int IW, int OH, int OW) {
    constexpr int NIN = 2 * NOX + 3;  // input values per (ic,ky) row
    int idx = blockIdx.x * 256 + threadIdx.x;
    int OWG = OW / NOX;
    int total = N * OH * OWG;
    if (idx >= total) return;
    int oxg = idx % OWG;
    int r = idx / OWG;
    int oy = r % OH;
    int n = r / OH;
    int ox0 = oxg * NOX;

    float acc[OC * NOX];
#pragma unroll
    for (int o = 0; o < OC; o++) {
        float b = bias[o];
#pragma unroll
        for (int j = 0; j < NOX; j++) acc[o * NOX + j] = b;
    }

    int iy0 = oy * 2 - 2;
    int ix0 = ox0 * 2 - 2;
    const float* inb = in + (size_t)n * IC * IH * IW;

    for (int ic = 0; ic < IC; ic++) {
        const float* inc = inb + (size_t)ic * IH * IW;
#pragma unroll
        for (int ky = 0; ky < 5; ky++) {
            int iy = iy0 + ky;
            bool vy = (iy >= 0) & (iy < IH);
            const float* row = inc + (size_t)(vy ? iy : 0) * IW;
            float xr[NIN];
#pragma unroll
            for (int i = 0; i < NIN; i++) {
                int ix = ix0 + i;
                bool v = vy & (ix >= 0) & (ix < IW);
                xr[i] = v ? row[ix] : 0.0f;
            }
#pragma unroll
            for (int kx = 0; kx < 5; kx++) {
                const float* wp = wt + (ic * 25 + ky * 5 + kx) * OC;
#pragma unroll
                for (int o4 = 0; o4 < OC; o4 += 4) {
                    float4 w = *(const float4*)(wp + o4);
#pragma unroll
                    for (int j = 0; j < NOX; j++) {
                        float x = xr[kx + 2 * j];
                        acc[(o4 + 0) * NOX + j] = fmaf(x, w.x, acc[(o4 + 0) * NOX + j]);
                        acc[(o4 + 1) * NOX + j] = fmaf(x, w.y, acc[(o4 + 1) * NOX + j]);
                        acc[(o4 + 2) * NOX + j] = fmaf(x, w.z, acc[(o4 + 2) * NOX + j]);
                        acc[(o4 + 3) * NOX + j] = fmaf(x, w.w, acc[(o4 + 3) * NOX + j]);
                    }
                }
            }
        }
    }

    size_t ohw = (size_t)OH * OW;
    float* ob = out + (size_t)n * OC * ohw + (size_t)oy * OW + ox0;
#pragma unroll
    for (int o = 0; o < OC; o++) {
        if constexpr (NOX == 4) {
            float4 v;
            v.x = fmaxf(acc[o * 4 + 0], 0.0f);
            v.y = fmaxf(acc[o * 4 + 1], 0.0f);
            v.z = fmaxf(acc[o * 4 + 2], 0.0f);
            v.w = fmaxf(acc[o * 4 + 3], 0.0f);
            *(float4*)(ob + (size_t)o * ohw) = v;
        } else if constexpr (NOX == 2) {
            float2 v;
            v.x = fmaxf(acc[o * 2 + 0], 0.0f);
            v.y = fmaxf(acc[o * 2 + 1], 0.0f);
            *(float2*)(ob + (size_t)o * ohw) = v;
        } else {
#pragma unroll
            for (int j = 0; j < NOX; j++)
                ob[(size_t)o * ohw + j] = fmaxf(acc[o * NOX + j], 0.0f);
        }
    }
}

// ---------------- head: feats[n, f*8+k] = sum_p x[n,f,p] * hw[f,p,k] + hb[f,k] ----------------
__global__ void head_kernel(const float* __restrict__ x, const float* __restrict__ hw,
                            const float* __restrict__ hb, float* __restrict__ feats) {
    int n = blockIdx.x;      // 0..127
    int tid = threadIdx.x;   // 0..63
    int f = tid >> 3;
    int k = tid & 7;
    const float* xb = x + (size_t)n * NF * 800 + (size_t)f * 800;
    const float* wb = hw + (size_t)f * 800 * FPF + k;
    float acc = hb[tid];
    for (int p = 0; p < 800; p++) acc = fmaf(xb[p], wb[(size_t)p * FPF], acc);
    feats[n * 64 + tid] = acc;
}

// ---------------- global std (ddof=1) over 8192 feats -> invstd ----------------
__global__ void stats_kernel(const float* __restrict__ feats, float* __restrict__ invstd) {
    __shared__ float s_sum[256], s_sq[256];
    int tid = threadIdx.x;
    float s = 0.0f, q = 0.0f;
    for (int i = tid; i < 8192; i += 256) {
        float x = feats[i];
        s += x;
        q += x * x;
    }
    s_sum[tid] = s;
    s_sq[tid] = q;
    __syncthreads();
    for (int off = 128; off > 0; off >>= 1) {
        if (tid < off) {
            s_sum[tid] += s_sum[tid + off];
            s_sq[tid] += s_sq[tid + off];
        }
        __syncthreads();
    }
    if (tid == 0) {
        float mean = s_sum[0] / 8192.0f;
        float var = (s_sq[0] - 8192.0f * mean * mean) / 8191.0f;
        var = fmaxf(var, 0.0f);
        invstd[0] = 1.0f / (sqrtf(var) + 1e-5f);
    }
}

// ---------------- speed embedding ----------------
__global__ void semb_kernel(const float* __restrict__ speed, const float* __restrict__ w1,
                            const float* __restrict__ b1, const float* __restrict__ w2,
                            const float* __restrict__ b2, float* __restrict__ emb) {
    int n = threadIdx.x;  // 0..127
    float s = speed[n];
    float h[16];
#pragma unroll
    for (int j = 0; j < 16; j++) h[j] = fmaxf(fmaf(s, w1[j], b1[j]), 0.0f);
#pragma unroll
    for (int k = 0; k < SDIM; k++) {
        float a = b2[k];
#pragma unroll
        for (int j = 0; j < 16; j++) a = fmaf(h[j], w2[j * SDIM + k], a);
        emb[n * SDIM + k] = tanhf(a);
    }
}

// ---------------- sensory precompute ----------------
__global__ void sensory_kernel(const float* __restrict__ feats, const float* __restrict__ emb,
                               const float* __restrict__ invstd, const float* __restrict__ inw,
                               const float* __restrict__ inb, const float* __restrict__ ssig,
                               const float* __restrict__ smu, const float* __restrict__ sw,
                               const float* __restrict__ serev, float* __restrict__ wns,
                               float* __restrict__ wds) {
    int bid = blockIdx.x;    // t*4 + b
    int t = bid >> 2;
    int b = bid & 3;
    int u = threadIdx.x;     // 0..63
    int n = b * TT + t;
    float inv = invstd[0];
    float num = 0.0f, den = 0.0f;
    for (int s = 0; s < SS; s++) {
        float xsv = (s < 64) ? feats[n * 64 + s] * inv : emb[n * SDIM + (s - 64)];
        float inp = fmaf(xsv, inw[s], inb[s]);
        int idx = s * UU + u;
        float x = (inp - smu[idx]) * ssig[idx];
        float act = sw[idx] * fast_sigmoid(x);
        num = fmaf(act, serev[idx], num);
        den += act;
    }
    wns[bid * UU + u] = num;
    wds[bid * UU + u] = den;
}

// ---------------- LTC scan: 4 blocks (one per batch), 256 threads ----------------
__global__ __launch_bounds__(256) void scan_kernel(
    const float* __restrict__ wns, const float* __restrict__ wds,
    const float* __restrict__ gleak, const float* __restrict__ vleak,
    const float* __restrict__ cm, const float* __restrict__ sigma,
    const float* __restrict__ mu, const float* __restrict__ wsyn,
    const float* __restrict__ erev, const float* __restrict__ outw,
    const float* __restrict__ outb, float* __restrict__ dout) {
    int b = blockIdx.x;
    int tid = threadIdx.x;
    int u = tid & 63;
    int pc = tid >> 6;  // 0..3

    __shared__ float vsh[64];
    __shared__ float pn[4][64], pd[4][64];

    float p_sig[16], p_mu[16], p_w[16], p_er[16];
#pragma unroll
    for (int i = 0; i < 16; i++) {
        int pre = pc * 16 + i;
        p_sig[i] = sigma[pre * UU + u];
        p_mu[i] = mu[pre * UU + u];
        p_w[i] = wsyn[pre * UU + u];
        p_er[i] = erev[pre * UU + u];
    }
    float cmt = cm[u] * (float)UNFOLDS;
    float gl = gleak[u];
    float glvl = gl * vleak[u];
    float v_u = 0.0f;
    if (tid < 64) vsh[u] = 0.0f;
    __syncthreads();

    for (int t = 0; t < TT; t++) {
        float num_s = wns[(t * BB + b) * UU + u];
        float den_s = wds[(t * BB + b) * UU + u];
        for (int k = 0; k < UNFOLDS; k++) {
            float num = 0.0f, den = 0.0f;
#pragma unroll
            for (int i = 0; i < 16; i++) {
                float x = (vsh[pc * 16 + i] - p_mu[i]) * p_sig[i];
                float a = p_w[i] * fast_sigmoid(x);
                num = fmaf(a, p_er[i], num);
                den += a;
            }
            pn[pc][u] = num;
            pd[pc][u] = den;
            __syncthreads();
            if (tid < 64) {
                float nn = pn[0][u] + pn[1][u] + pn[2][u] + pn[3][u] + num_s;
                float dd = pd[0][u] + pd[1][u] + pd[2][u] + pd[3][u] + den_s;
                v_u = (cmt * v_u + glvl + nn) / (cmt + gl + dd + 1e-8f);
                vsh[u] = v_u;
            }
            __syncthreads();
        }
        if (tid < 64) {
            dout[384 + (b * TT + t) * UU + u] = v_u;
            if (u == 0) dout[b * TT + t] = fmaf(v_u, outw[0], outb[0]);
            if (t == TT - 1) dout[128 + b * UU + u] = v_u;
        }
    }
}

extern "C" void kernel_launch(void* const* d_in, const int* in_sizes, int n_in,
                              void* d_out, int out_size, void* d_ws, size_t ws_size,
                              hipStream_t stream) {
    const float* in_seq = (const float*)d_in[0];
    const float* speed = (const float*)d_in[1];
    const float* c1w = (const float*)d_in[2];
    const float* c1b = (const float*)d_in[3];
    const float* c2w = (const float*)d_in[4];
    const float* c2b = (const float*)d_in[5];
    const float* c3w = (const float*)d_in[6];
    const float* c3b = (const float*)d_in[7];
    const float* hw = (const float*)d_in[8];
    const float* hb = (const float*)d_in[9];
    const float* sew1 = (const float*)d_in[10];
    const float* seb1 = (const float*)d_in[11];
    const float* sew2 = (const float*)d_in[12];
    const float* seb2 = (const float*)d_in[13];
    const float* inw = (const float*)d_in[14];
    const float* inb = (const float*)d_in[15];
    const float* gleak = (const float*)d_in[16];
    const float* vleak = (const float*)d_in[17];
    const float* cm = (const float*)d_in[18];
    const float* sigma = (const float*)d_in[19];
    const float* mu = (const float*)d_in[20];
    const float* wsyn = (const float*)d_in[21];
    const float* erev = (const float*)d_in[22];
    const float* ssig = (const float*)d_in[23];
    const float* smu = (const float*)d_in[24];
    const float* sw = (const float*)d_in[25];
    const float* serev = (const float*)d_in[26];
    const float* outw = (const float*)d_in[27];
    const float* outb = (const float*)d_in[28];

    float* ws = (float*)d_ws;
    float* out = (float*)d_out;

    // workspace layout (floats)
    size_t o_c1 = 0;
    size_t o_c2 = o_c1 + (size_t)128 * 16 * 80 * 160;
    size_t o_c3 = o_c2 + (size_t)128 * 32 * 40 * 80;
    size_t o_ft = o_c3 + (size_t)128 * 8 * 800;
    size_t o_emb = o_ft + 8192;
    size_t o_inv = o_emb + 1024;
    size_t o_wns = o_inv + 16;
    size_t o_wds = o_wns + 8192;
    size_t o_w1 = o_wds + 8192;
    size_t o_w2 = o_w1 + 1200;
    size_t o_w3 = o_w2 + 12800;

    float* c1out = ws + o_c1;
    float* c2out = ws + o_c2;
    float* c3out = ws + o_c3;
    float* feats = ws + o_ft;
    float* emb = ws + o_emb;
    float* invstd = ws + o_inv;
    float* wns = ws + o_wns;
    float* wds = ws + o_wds;
    float* wt1 = ws + o_w1;
    float* wt2 = ws + o_w2;
    float* wt3 = ws + o_w3;

    // weight transposes
    transpose_w_kernel<<<(16 * 3 * 25 + 255) / 256, 256, 0, stream>>>(c1w, wt1, 16, 3);
    transpose_w_kernel<<<(32 * 16 * 25 + 255) / 256, 256, 0, stream>>>(c2w, wt2, 32, 16);
    transpose_w_kernel<<<(8 * 32 * 25 + 255) / 256, 256, 0, stream>>>(c3w, wt3, 8, 32);

    // convs: multi-output-per-thread, high FMA density
    // conv1: 128*80*(160/4) = 409600 threads
    conv5x5_multi<3, 16, 4><<<409600 / 256, 256, 0, stream>>>(
        in_seq, wt1, c1b, c1out, 128, 160, 320, 80, 160);
    // conv2: 128*40*(80/2) = 204800 threads
    conv5x5_multi<16, 32, 2><<<204800 / 256, 256, 0, stream>>>(
        c1out, wt2, c2b, c2out, 128, 80, 160, 40, 80);
    // conv3: 128*20*(40/4) = 25600 threads
    conv5x5_multi<32, 8, 4><<<25600 / 256, 256, 0, stream>>>(
        c2out, wt3, c3b, c3out, 128, 40, 80, 20, 40);

    // head + stats + speed embedding
    head_kernel<<<128, 64, 0, stream>>>(c3out, hw, hb, feats);
    stats_kernel<<<1, 256, 0, stream>>>(feats, invstd);
    semb_kernel<<<1, 128, 0, stream>>>(speed, sew1, seb1, sew2, seb2, emb);

    // sensory precompute
    sensory_kernel<<<TT * BB, 64, 0, stream>>>(feats, emb, invstd, inw, inb, ssig, smu, sw,
                                               serev, wns, wds);

    // serial LTC scan
    scan_kernel<<<BB, 256, 0, stream>>>(wns, wds, gleak, vleak, cm, sigma, mu, wsyn, erev,
                                        outw, outb, out);
}

// Round 4
// 325.245 us; speedup vs baseline: 3.0730x; 3.0730x over previous
//
#include <hip/hip_runtime.h>
#include <math.h>

// Problem constants
#define BB 4
#define TT 32
#define NF 8
#define FPF 8
#define SDIM 8
#define UU 64
#define SS 72
#define UNFOLDS 6

typedef short short8 __attribute__((ext_vector_type(8)));
typedef float f32x4 __attribute__((ext_vector_type(4)));
union Frag { uint4 u; short8 s; };

__device__ __forceinline__ float fast_sigmoid(float x) {
    float e = exp2f(-1.44269504f * x);
    return __builtin_amdgcn_rcpf(1.0f + e);
}

// fp32 -> bf16 bits, round-to-nearest-even (inputs finite)
__device__ __forceinline__ ushort f2b(float f) {
    union { float f; uint u; } a;
    a.f = f;
    uint u = a.u;
    return (ushort)((u + 0x7FFFu + ((u >> 16) & 1u)) >> 16);
}

// ============ input f32 NCHW -> padded NHWC bf16 [128][164][328][4] (c3=0) ============
__global__ __launch_bounds__(256) void cvt_input(const float* __restrict__ in,
                                                 ushort* __restrict__ outp) {
    int idx = blockIdx.x * 256 + threadIdx.x;
    if (idx >= 128 * 160 * 320) return;
    int x = idx % 320;
    int r = idx / 320;
    int y = r % 160;
    int n = r / 160;
    const float* base = in + ((size_t)n * 3 * 160 + y) * 320 + x;
    float c0 = base[0];
    float c1 = base[160 * 320];
    float c2 = base[2 * 160 * 320];
    uint2 pk;
    pk.x = (uint)f2b(c0) | ((uint)f2b(c1) << 16);
    pk.y = (uint)f2b(c2);
    *(uint2*)(outp + ((size_t)((n * 164 + y + 2) * 328) + (x + 2)) * 4) = pk;
}

// ============ halo zero fills ============
__global__ __launch_bounds__(256) void fill_halo1(ushort* buf) {  // [128][164][328][4]
    int idx = blockIdx.x * 256 + threadIdx.x;
    if (idx >= 128 * 164 * 328) return;
    int x = idx % 328;
    int y = (idx / 328) % 164;
    if (y >= 2 && y < 162 && x >= 2 && x < 322) return;
    *(uint2*)(buf + (size_t)idx * 4) = make_uint2(0u, 0u);
}
__global__ __launch_bounds__(256) void fill_halo2(ushort* buf) {  // [128][84][164][16]
    int idx = blockIdx.x * 256 + threadIdx.x;
    if (idx >= 128 * 84 * 164) return;
    int x = idx % 164;
    int y = (idx / 164) % 84;
    if (y >= 2 && y < 82 && x >= 2 && x < 162) return;
    uint4 z = make_uint4(0u, 0u, 0u, 0u);
    *(uint4*)(buf + (size_t)idx * 16) = z;
    *(uint4*)(buf + (size_t)idx * 16 + 8) = z;
}
__global__ __launch_bounds__(256) void fill_halo3(ushort* buf) {  // [128][44][84][32]
    int idx = blockIdx.x * 256 + threadIdx.x;
    if (idx >= 128 * 44 * 84) return;
    int x = idx % 84;
    int y = (idx / 84) % 44;
    if (y >= 2 && y < 42 && x >= 2 && x < 82) return;
    uint4 z = make_uint4(0u, 0u, 0u, 0u);
#pragma unroll
    for (int i = 0; i < 4; i++) *(uint4*)(buf + (size_t)idx * 32 + i * 8) = z;
}

// ============ weight swizzles into MFMA A-fragment layout ============
// A-frag (16x16x32): row(oc)=lane&15, k=(lane>>4)*8+j
__global__ void wswz1_kernel(const float* __restrict__ w, uint4* __restrict__ o) {
    int i = blockIdx.x * 64 + threadIdx.x;  // [5 ky][64 lanes]
    if (i >= 5 * 64) return;
    int lane = i & 63, s = i >> 6;
    int oc = lane & 15, q = lane >> 4;
    ushort v[8];
#pragma unroll
    for (int j = 0; j < 8; j++) {
        int k = q * 8 + j;
        int kx = k >> 2, c = k & 3;  // 8 horiz pixels x 4 ch
        float f = (kx < 5 && c < 3) ? w[((oc * 3 + c) * 5 + s) * 5 + kx] : 0.f;
        v[j] = f2b(f);
    }
    uint4 u;
    u.x = (uint)v[0] | ((uint)v[1] << 16);
    u.y = (uint)v[2] | ((uint)v[3] << 16);
    u.z = (uint)v[4] | ((uint)v[5] << 16);
    u.w = (uint)v[6] | ((uint)v[7] << 16);
    o[i] = u;
}
__global__ void wswz2_kernel(const float* __restrict__ w, uint4* __restrict__ o) {
    int i = blockIdx.x * 64 + threadIdx.x;  // [15 kstep][2 octile][64]
    if (i >= 15 * 2 * 64) return;
    int lane = i & 63;
    int ct = (i >> 6) & 1;
    int s = i >> 7;
    int ky = s / 3, kxp = s % 3;
    int oc = ct * 16 + (lane & 15);
    int q = lane >> 4, h = q >> 1;
    int kx = 2 * kxp + h;
    ushort v[8];
#pragma unroll
    for (int j = 0; j < 8; j++) {
        int ch = (q & 1) * 8 + j;
        float f = (kx < 5) ? w[((oc * 16 + ch) * 5 + ky) * 5 + kx] : 0.f;
        v[j] = f2b(f);
    }
    uint4 u;
    u.x = (uint)v[0] | ((uint)v[1] << 16);
    u.y = (uint)v[2] | ((uint)v[3] << 16);
    u.z = (uint)v[4] | ((uint)v[5] << 16);
    u.w = (uint)v[6] | ((uint)v[7] << 16);
    o[i] = u;
}
__global__ void wswz3_kernel(const float* __restrict__ w, uint4* __restrict__ o) {
    int i = blockIdx.x * 64 + threadIdx.x;  // [25 tap][64]
    if (i >= 25 * 64) return;
    int lane = i & 63, s = i >> 6;
    int ky = s / 5, kx = s % 5;
    int oc = lane & 15, q = lane >> 4;
    ushort v[8];
#pragma unroll
    for (int j = 0; j < 8; j++) {
        int ch = q * 8 + j;
        float f = (oc < 8) ? w[((oc * 32 + ch) * 5 + ky) * 5 + kx] : 0.f;
        v[j] = f2b(f);
    }
    uint4 u;
    u.x = (uint)v[0] | ((uint)v[1] << 16);
    u.y = (uint)v[2] | ((uint)v[3] << 16);
    u.z = (uint)v[4] | ((uint)v[5] << 16);
    u.w = (uint)v[6] | ((uint)v[7] << 16);
    o[i] = u;
}

// ============ conv1: [128][164][328][4] -> [128][84][164][16], 5 ksteps (ky) ============
__global__ __launch_bounds__(256) void conv1_mfma(const ushort* __restrict__ inp,
                                                  const uint4* __restrict__ wswz,
                                                  const float* __restrict__ bias,
                                                  ushort* __restrict__ outp) {
    const int lane = threadIdx.x & 63;
    const int wid = threadIdx.x >> 6;
    const int col = lane & 15, q = lane >> 4;

    Frag A[5];
#pragma unroll
    for (int s = 0; s < 5; s++) A[s].u = wswz[s * 64 + lane];
    float b0 = bias[q * 4 + 0], b1 = bias[q * 4 + 1], b2 = bias[q * 4 + 2], b3 = bias[q * 4 + 3];

    int gw = blockIdx.x * 4 + wid;
#pragma unroll
    for (int t = 0; t < 4; t++) {
        int p0 = gw * 64 + t * 16;
        int n = p0 / 12800;
        int rem = p0 - n * 12800;
        int oy = rem / 160;
        int ox0 = rem - oy * 160;     // OW=160 multiple of 16: no row-cross
        int ox = ox0 + col;
        uint e0 = ((uint)(n * 164 + oy * 2) * 328u + (uint)(ox * 2 + 2 * q)) * 4u;
        f32x4 acc = {0.f, 0.f, 0.f, 0.f};
#pragma unroll
        for (int s = 0; s < 5; s++) {
            Frag B;
            B.u = *(const uint4*)(inp + e0 + (uint)s * (328u * 4u));
            acc = __builtin_amdgcn_mfma_f32_16x16x32_bf16(A[s].s, B.s, acc, 0, 0, 0);
        }
        uint oe = ((uint)(n * 84 + oy + 2) * 164u + (uint)(ox + 2)) * 16u + q * 4u;
        uint2 pk;
        pk.x = (uint)f2b(fmaxf(acc[0] + b0, 0.f)) | ((uint)f2b(fmaxf(acc[1] + b1, 0.f)) << 16);
        pk.y = (uint)f2b(fmaxf(acc[2] + b2, 0.f)) | ((uint)f2b(fmaxf(acc[3] + b3, 0.f)) << 16);
        *(uint2*)(outp + oe) = pk;
    }
}

// ============ conv2: [128][84][164][16] -> [128][44][84][32], 15 ksteps ============
__global__ __launch_bounds__(256) void conv2_mfma(const ushort* __restrict__ inp,
                                                  const uint4* __restrict__ wswz,
                                                  const float* __restrict__ bias,
                                                  ushort* __restrict__ outp) {
    const int lane = threadIdx.x & 63;
    const int wid = threadIdx.x >> 6;
    const int col = lane & 15, q = lane >> 4;
    const int h = q >> 1, chh = q & 1;

    int gw = blockIdx.x * 4 + wid;
    uint eb[4];
#pragma unroll
    for (int t = 0; t < 4; t++) {
        int p0 = gw * 64 + t * 16;
        int n = p0 / 3200;
        int rem = p0 - n * 3200;
        int oy = rem / 80;
        int ox0 = rem - oy * 80;      // OW=80 multiple of 16: no row-cross
        eb[t] = ((uint)(n * 84 + oy * 2) * 164u + (uint)((ox0 + col) * 2 + h)) * 16u + chh * 8u;
    }
    f32x4 acc[4][2];
#pragma unroll
    for (int t = 0; t < 4; t++) {
        acc[t][0] = {0.f, 0.f, 0.f, 0.f};
        acc[t][1] = {0.f, 0.f, 0.f, 0.f};
    }
#pragma unroll
    for (int s = 0; s < 15; s++) {
        const int ky = s / 3, kxp = s % 3;
        Frag A0, A1;
        A0.u = wswz[(s * 2 + 0) * 64 + lane];
        A1.u = wswz[(s * 2 + 1) * 64 + lane];
        const uint d = (uint)ky * (164u * 16u) + (uint)kxp * 32u;
#pragma unroll
        for (int t = 0; t < 4; t++) {
            Frag B;
            B.u = *(const uint4*)(inp + eb[t] + d);
            acc[t][0] = __builtin_amdgcn_mfma_f32_16x16x32_bf16(A0.s, B.s, acc[t][0], 0, 0, 0);
            acc[t][1] = __builtin_amdgcn_mfma_f32_16x16x32_bf16(A1.s, B.s, acc[t][1], 0, 0, 0);
        }
    }
    float ba[2][4];
#pragma unroll
    for (int c = 0; c < 2; c++)
#pragma unroll
        for (int r = 0; r < 4; r++) ba[c][r] = bias[c * 16 + q * 4 + r];
#pragma unroll
    for (int t = 0; t < 4; t++) {
        int p0 = gw * 64 + t * 16;
        int n = p0 / 3200;
        int rem = p0 - n * 3200;
        int oy = rem / 80;
        int ox0 = rem - oy * 80;
        int ox = ox0 + col;
        uint oe = ((uint)(n * 44 + oy + 2) * 84u + (uint)(ox + 2)) * 32u;
#pragma unroll
        for (int c = 0; c < 2; c++) {
            uint2 pk;
            pk.x = (uint)f2b(fmaxf(acc[t][c][0] + ba[c][0], 0.f)) |
                   ((uint)f2b(fmaxf(acc[t][c][1] + ba[c][1], 0.f)) << 16);
            pk.y = (uint)f2b(fmaxf(acc[t][c][2] + ba[c][2], 0.f)) |
                   ((uint)f2b(fmaxf(acc[t][c][3] + ba[c][3], 0.f)) << 16);
            *(uint2*)(outp + oe + (uint)c * 16u + (uint)q * 4u) = pk;
        }
    }
}

// ============ conv3: [128][44][84][32] -> [128][800][8] f32 (NHWC), 25 ksteps ============
__global__ __launch_bounds__(256) void conv3_mfma(const ushort* __restrict__ inp,
                                                  const uint4* __restrict__ wswz,
                                                  const float* __restrict__ bias,
                                                  float* __restrict__ outp) {
    const int lane = threadIdx.x & 63;
    const int wid = threadIdx.x >> 6;
    const int col = lane & 15, q = lane >> 4;

    int gw = blockIdx.x * 4 + wid;
    uint eb[4];
#pragma unroll
    for (int t = 0; t < 4; t++) {
        int p0 = gw * 64 + t * 16;
        int n = p0 / 800;
        // OW=40 is NOT a multiple of 16: compute per-lane pixel coords (fixes
        // the row-crossing bug from R3 — tile pixels may wrap to the next row).
        int pix = p0 - n * 800 + col;
        int oy = pix / 40;
        int ox = pix - oy * 40;
        eb[t] = ((uint)(n * 44 + oy * 2) * 84u + (uint)(ox * 2)) * 32u + q * 8u;
    }
    f32x4 acc[4];
#pragma unroll
    for (int t = 0; t < 4; t++) acc[t] = {0.f, 0.f, 0.f, 0.f};
#pragma unroll
    for (int s = 0; s < 25; s++) {
        const int ky = s / 5, kx = s % 5;
        Frag A;
        A.u = wswz[s * 64 + lane];
        const uint d = ((uint)ky * 84u + (uint)kx) * 32u;
#pragma unroll
        for (int t = 0; t < 4; t++) {
            Frag B;
            B.u = *(const uint4*)(inp + eb[t] + d);
            acc[t] = __builtin_amdgcn_mfma_f32_16x16x32_bf16(A.s, B.s, acc[t], 0, 0, 0);
        }
    }
    if (q < 2) {
        float b0 = bias[q * 4 + 0], b1 = bias[q * 4 + 1];
        float b2 = bias[q * 4 + 2], b3 = bias[q * 4 + 3];
#pragma unroll
        for (int t = 0; t < 4; t++) {
            int p0 = gw * 64 + t * 16;
            int n = p0 / 800;
            int p = p0 - n * 800 + col;  // global pixel in image (0..799)
            float4 v;
            v.x = fmaxf(acc[t][0] + b0, 0.f);
            v.y = fmaxf(acc[t][1] + b1, 0.f);
            v.z = fmaxf(acc[t][2] + b2, 0.f);
            v.w = fmaxf(acc[t][3] + b3, 0.f);
            *(float4*)(outp + ((size_t)n * 800 + p) * 8 + q * 4) = v;
        }
    }
}

// ============ head: feats[n, f*8+k] = sum_p x[n,p,f] * hw[f,p,k] + hb[f,k] ============
__global__ void head_kernel(const float* __restrict__ x, const float* __restrict__ hw,
                            const float* __restrict__ hb, float* __restrict__ feats) {
    int n = blockIdx.x;
    int tid = threadIdx.x;  // 0..63
    int f = tid >> 3;
    int k = tid & 7;
    const float* xb = x + (size_t)n * 800 * 8 + f;
    const float* wb = hw + ((size_t)f * 800) * FPF + k;
    float acc = hb[tid];
    for (int p = 0; p < 800; p++) acc = fmaf(xb[(size_t)p * 8], wb[(size_t)p * FPF], acc);
    feats[n * 64 + tid] = acc;
}

// ============ global std (ddof=1) ============
__global__ void stats_kernel(const float* __restrict__ feats, float* __restrict__ invstd) {
    __shared__ float s_sum[256], s_sq[256];
    int tid = threadIdx.x;
    float s = 0.0f, q = 0.0f;
    for (int i = tid; i < 8192; i += 256) {
        float x = feats[i];
        s += x;
        q += x * x;
    }
    s_sum[tid] = s;
    s_sq[tid] = q;
    __syncthreads();
    for (int off = 128; off > 0; off >>= 1) {
        if (tid < off) {
            s_sum[tid] += s_sum[tid + off];
            s_sq[tid] += s_sq[tid + off];
        }
        __syncthreads();
    }
    if (tid == 0) {
        float mean = s_sum[0] / 8192.0f;
        float var = (s_sq[0] - 8192.0f * mean * mean) / 8191.0f;
        var = fmaxf(var, 0.0f);
        invstd[0] = 1.0f / (sqrtf(var) + 1e-5f);
    }
}

// ============ speed embedding ============
__global__ void semb_kernel(const float* __restrict__ speed, const float* __restrict__ w1,
                            const float* __restrict__ b1, const float* __restrict__ w2,
                            const float* __restrict__ b2, float* __restrict__ emb) {
    int n = threadIdx.x;  // 0..127
    float s = speed[n];
    float h[16];
#pragma unroll
    for (int j = 0; j < 16; j++) h[j] = fmaxf(fmaf(s, w1[j], b1[j]), 0.0f);
#pragma unroll
    for (int k = 0; k < SDIM; k++) {
        float a = b2[k];
#pragma unroll
        for (int j = 0; j < 16; j++) a = fmaf(h[j], w2[j * SDIM + k], a);
        emb[n * SDIM + k] = tanhf(a);
    }
}

// ============ sensory precompute ============
__global__ void sensory_kernel(const float* __restrict__ feats, const float* __restrict__ emb,
                               const float* __restrict__ invstd, const float* __restrict__ inw,
                               const float* __restrict__ inb, const float* __restrict__ ssig,
                               const float* __restrict__ smu, const float* __restrict__ sw,
                               const float* __restrict__ serev, float* __restrict__ wns,
                               float* __restrict__ wds) {
    int bid = blockIdx.x;  // t*4 + b
    int t = bid >> 2;
    int b = bid & 3;
    int u = threadIdx.x;  // 0..63
    int n = b * TT + t;
    float inv = invstd[0];
    float num = 0.0f, den = 0.0f;
    for (int s = 0; s < SS; s++) {
        float xsv = (s < 64) ? feats[n * 64 + s] * inv : emb[n * SDIM + (s - 64)];
        float inp = fmaf(xsv, inw[s], inb[s]);
        int idx = s * UU + u;
        float x = (inp - smu[idx]) * ssig[idx];
        float act = sw[idx] * fast_sigmoid(x);
        num = fmaf(act, serev[idx], num);
        den += act;
    }
    wns[bid * UU + u] = num;
    wds[bid * UU + u] = den;
}

// ============ LTC scan ============
__global__ __launch_bounds__(256) void scan_kernel(
    const float* __restrict__ wns, const float* __restrict__ wds,
    const float* __restrict__ gleak, const float* __restrict__ vleak,
    const float* __restrict__ cm, const float* __restrict__ sigma,
    const float* __restrict__ mu, const float* __restrict__ wsyn,
    const float* __restrict__ erev, const float* __restrict__ outw,
    const float* __restrict__ outb, float* __restrict__ dout) {
    int b = blockIdx.x;
    int tid = threadIdx.x;
    int u = tid & 63;
    int pc = tid >> 6;

    __shared__ float vsh[64];
    __shared__ float pn[4][64], pd[4][64];

    float p_sig[16], p_mu[16], p_w[16], p_er[16];
#pragma unroll
    for (int i = 0; i < 16; i++) {
        int pre = pc * 16 + i;
        p_sig[i] = sigma[pre * UU + u];
        p_mu[i] = mu[pre * UU + u];
        p_w[i] = wsyn[pre * UU + u];
        p_er[i] = erev[pre * UU + u];
    }
    float cmt = cm[u] * (float)UNFOLDS;
    float gl = gleak[u];
    float glvl = gl * vleak[u];
    float v_u = 0.0f;
    if (tid < 64) vsh[u] = 0.0f;
    __syncthreads();

    for (int t = 0; t < TT; t++) {
        float num_s = wns[(t * BB + b) * UU + u];
        float den_s = wds[(t * BB + b) * UU + u];
        for (int k = 0; k < UNFOLDS; k++) {
            float num = 0.0f, den = 0.0f;
#pragma unroll
            for (int i = 0; i < 16; i++) {
                float x = (vsh[pc * 16 + i] - p_mu[i]) * p_sig[i];
                float a = p_w[i] * fast_sigmoid(x);
                num = fmaf(a, p_er[i], num);
                den += a;
            }
            pn[pc][u] = num;
            pd[pc][u] = den;
            __syncthreads();
            if (tid < 64) {
                float nn = pn[0][u] + pn[1][u] + pn[2][u] + pn[3][u] + num_s;
                float dd = pd[0][u] + pd[1][u] + pd[2][u] + pd[3][u] + den_s;
                v_u = (cmt * v_u + glvl + nn) / (cmt + gl + dd + 1e-8f);
                vsh[u] = v_u;
            }
            __syncthreads();
        }
        if (tid < 64) {
            dout[384 + (b * TT + t) * UU + u] = v_u;
            if (u == 0) dout[b * TT + t] = fmaf(v_u, outw[0], outb[0]);
            if (t == TT - 1) dout[128 + b * UU + u] = v_u;
        }
    }
}

extern "C" void kernel_launch(void* const* d_in, const int* in_sizes, int n_in,
                              void* d_out, int out_size, void* d_ws, size_t ws_size,
                              hipStream_t stream) {
    const float* in_seq = (const float*)d_in[0];
    const float* speed = (const float*)d_in[1];
    const float* c1w = (const float*)d_in[2];
    const float* c1b = (const float*)d_in[3];
    const float* c2w = (const float*)d_in[4];
    const float* c2b = (const float*)d_in[5];
    const float* c3w = (const float*)d_in[6];
    const float* c3b = (const float*)d_in[7];
    const float* hw = (const float*)d_in[8];
    const float* hb = (const float*)d_in[9];
    const float* sew1 = (const float*)d_in[10];
    const float* seb1 = (const float*)d_in[11];
    const float* sew2 = (const float*)d_in[12];
    const float* seb2 = (const float*)d_in[13];
    const float* inw = (const float*)d_in[14];
    const float* inb = (const float*)d_in[15];
    const float* gleak = (const float*)d_in[16];
    const float* vleak = (const float*)d_in[17];
    const float* cm = (const float*)d_in[18];
    const float* sigma = (const float*)d_in[19];
    const float* mu = (const float*)d_in[20];
    const float* wsyn = (const float*)d_in[21];
    const float* erev = (const float*)d_in[22];
    const float* ssig = (const float*)d_in[23];
    const float* smu = (const float*)d_in[24];
    const float* sw = (const float*)d_in[25];
    const float* serev = (const float*)d_in[26];
    const float* outw = (const float*)d_in[27];
    const float* outb = (const float*)d_in[28];

    char* ws = (char*)d_ws;
    float* out = (float*)d_out;

    // byte layout
    size_t off = 0;
    auto alloc = [&](size_t bytes) {
        size_t o = off;
        off += (bytes + 255) & ~(size_t)255;
        return o;
    };
    ushort* inp1 = (ushort*)(ws + alloc((size_t)128 * 164 * 328 * 4 * 2));
    ushort* c1out = (ushort*)(ws + alloc((size_t)128 * 84 * 164 * 16 * 2));
    ushort* c2out = (ushort*)(ws + alloc((size_t)128 * 44 * 84 * 32 * 2));
    float* c3out = (float*)(ws + alloc((size_t)128 * 800 * 8 * 4));
    float* feats = (float*)(ws + alloc(8192 * 4));
    float* emb = (float*)(ws + alloc(1024 * 4));
    float* invstd = (float*)(ws + alloc(64));
    float* wns = (float*)(ws + alloc(8192 * 4));
    float* wds = (float*)(ws + alloc(8192 * 4));
    uint4* wz1 = (uint4*)(ws + alloc(5 * 64 * 16));
    uint4* wz2 = (uint4*)(ws + alloc(30 * 64 * 16));
    uint4* wz3 = (uint4*)(ws + alloc(25 * 64 * 16));

    // weight swizzles
    wswz1_kernel<<<5, 64, 0, stream>>>(c1w, wz1);
    wswz2_kernel<<<30, 64, 0, stream>>>(c2w, wz2);
    wswz3_kernel<<<25, 64, 0, stream>>>(c3w, wz3);

    // halo fills + input conversion
    fill_halo1<<<26896, 256, 0, stream>>>(inp1);
    fill_halo2<<<6888, 256, 0, stream>>>(c1out);
    fill_halo3<<<1848, 256, 0, stream>>>(c2out);
    cvt_input<<<25600, 256, 0, stream>>>(in_seq, inp1);

    // MFMA convs
    conv1_mfma<<<6400, 256, 0, stream>>>(inp1, wz1, c1b, c1out);
    conv2_mfma<<<1600, 256, 0, stream>>>(c1out, wz2, c2b, c2out);
    conv3_mfma<<<400, 256, 0, stream>>>(c2out, wz3, c3b, c3out);

    // head + stats + speed embedding
    head_kernel<<<128, 64, 0, stream>>>(c3out, hw, hb, feats);
    stats_kernel<<<1, 256, 0, stream>>>(feats, invstd);
    semb_kernel<<<1, 128, 0, stream>>>(speed, sew1, seb1, sew2, seb2, emb);

    // sensory precompute
    sensory_kernel<<<TT * BB, 64, 0, stream>>>(feats, emb, invstd, inw, inb, ssig, smu, sw,
                                               serev, wns, wds);

    // serial LTC scan
    scan_kernel<<<BB, 256, 0, stream>>>(wns, wds, gleak, vleak, cm, sigma, mu, wsyn, erev,
                                        outw, outb, out);
}

// Round 5
// 293.421 us; speedup vs baseline: 3.4063x; 1.1085x over previous
//
#include <hip/hip_runtime.h>
#include <math.h>

// Problem constants
#define BB 4
#define TT 32
#define NF 8
#define FPF 8
#define SDIM 8
#define UU 64
#define SS 72
#define UNFOLDS 6

typedef short short8 __attribute__((ext_vector_type(8)));
typedef float f32x4 __attribute__((ext_vector_type(4)));
union Frag { uint4 u; short8 s; };

__device__ __forceinline__ float fast_sigmoid(float x) {
    float e = exp2f(-1.44269504f * x);
    return __builtin_amdgcn_rcpf(1.0f + e);
}

// fp32 -> bf16 bits, round-to-nearest-even (inputs finite)
__device__ __forceinline__ ushort f2b(float f) {
    union { float f; uint u; } a;
    a.f = f;
    uint u = a.u;
    return (ushort)((u + 0x7FFFu + ((u >> 16) & 1u)) >> 16);
}

__device__ __forceinline__ float bcast_lane(float v, int lane) {
    return __uint_as_float(__builtin_amdgcn_readlane(__float_as_uint(v), lane));
}

// ============ input f32 NCHW -> padded NHWC bf16 [128][164][328][4] (c3=0) ============
__global__ __launch_bounds__(256) void cvt_input(const float* __restrict__ in,
                                                 ushort* __restrict__ outp) {
    int idx = blockIdx.x * 256 + threadIdx.x;
    if (idx >= 128 * 160 * 320) return;
    int x = idx % 320;
    int r = idx / 320;
    int y = r % 160;
    int n = r / 160;
    const float* base = in + ((size_t)n * 3 * 160 + y) * 320 + x;
    float c0 = base[0];
    float c1 = base[160 * 320];
    float c2 = base[2 * 160 * 320];
    uint2 pk;
    pk.x = (uint)f2b(c0) | ((uint)f2b(c1) << 16);
    pk.y = (uint)f2b(c2);
    *(uint2*)(outp + ((size_t)((n * 164 + y + 2) * 328) + (x + 2)) * 4) = pk;
}

// ============ halo zero fill (halo-cells-only enumeration) ============
// frame [HP][WP] cells of CH ushorts; interior [2,2+H)x[2,2+W) untouched.
template <int HP, int WP, int H, int W, int CH>
__global__ __launch_bounds__(256) void fill_halo(ushort* __restrict__ buf) {
    constexpr int TOPBOT = 2 * WP;
    constexpr int SIDE = WP - W;  // cells per middle row (left 2 + right SIDE-2)
    constexpr int NH = 2 * TOPBOT + H * SIDE;
    int idx = blockIdx.x * 256 + threadIdx.x;
    if (idx >= 128 * NH) return;
    int n = idx / NH;
    int h = idx - n * NH;
    int y, x;
    if (h < TOPBOT) {
        y = h / WP;
        x = h % WP;
    } else if (h < 2 * TOPBOT) {
        int hh = h - TOPBOT;
        y = H + 2 + hh / WP;
        x = hh % WP;
    } else {
        int hh = h - 2 * TOPBOT;
        y = 2 + hh / SIDE;
        int xi = hh % SIDE;
        x = (xi < 2) ? xi : (W + xi);
    }
    ushort* p = buf + (((size_t)n * HP + y) * WP + x) * CH;
    if constexpr (CH == 4) {
        *(uint2*)p = make_uint2(0u, 0u);
    } else {
        uint4 z = make_uint4(0u, 0u, 0u, 0u);
#pragma unroll
        for (int i = 0; i < CH / 8; i++) *(uint4*)(p + i * 8) = z;
    }
}

// ============ weight swizzles into MFMA A-fragment layout ============
// A-frag (16x16x32): row(oc)=lane&15, k=(lane>>4)*8+j
__global__ void wswz1_kernel(const float* __restrict__ w, uint4* __restrict__ o) {
    int i = blockIdx.x * 64 + threadIdx.x;  // [5 ky][64 lanes]
    if (i >= 5 * 64) return;
    int lane = i & 63, s = i >> 6;
    int oc = lane & 15, q = lane >> 4;
    ushort v[8];
#pragma unroll
    for (int j = 0; j < 8; j++) {
        int k = q * 8 + j;
        int kx = k >> 2, c = k & 3;
        float f = (kx < 5 && c < 3) ? w[((oc * 3 + c) * 5 + s) * 5 + kx] : 0.f;
        v[j] = f2b(f);
    }
    uint4 u;
    u.x = (uint)v[0] | ((uint)v[1] << 16);
    u.y = (uint)v[2] | ((uint)v[3] << 16);
    u.z = (uint)v[4] | ((uint)v[5] << 16);
    u.w = (uint)v[6] | ((uint)v[7] << 16);
    o[i] = u;
}
__global__ void wswz2_kernel(const float* __restrict__ w, uint4* __restrict__ o) {
    int i = blockIdx.x * 64 + threadIdx.x;  // [15 kstep][2 octile][64]
    if (i >= 15 * 2 * 64) return;
    int lane = i & 63;
    int ct = (i >> 6) & 1;
    int s = i >> 7;
    int ky = s / 3, kxp = s % 3;
    int oc = ct * 16 + (lane & 15);
    int q = lane >> 4, h = q >> 1;
    int kx = 2 * kxp + h;
    ushort v[8];
#pragma unroll
    for (int j = 0; j < 8; j++) {
        int ch = (q & 1) * 8 + j;
        float f = (kx < 5) ? w[((oc * 16 + ch) * 5 + ky) * 5 + kx] : 0.f;
        v[j] = f2b(f);
    }
    uint4 u;
    u.x = (uint)v[0] | ((uint)v[1] << 16);
    u.y = (uint)v[2] | ((uint)v[3] << 16);
    u.z = (uint)v[4] | ((uint)v[5] << 16);
    u.w = (uint)v[6] | ((uint)v[7] << 16);
    o[i] = u;
}
__global__ void wswz3_kernel(const float* __restrict__ w, uint4* __restrict__ o) {
    int i = blockIdx.x * 64 + threadIdx.x;  // [25 tap][64]
    if (i >= 25 * 64) return;
    int lane = i & 63, s = i >> 6;
    int ky = s / 5, kx = s % 5;
    int oc = lane & 15, q = lane >> 4;
    ushort v[8];
#pragma unroll
    for (int j = 0; j < 8; j++) {
        int ch = q * 8 + j;
        float f = (oc < 8) ? w[((oc * 32 + ch) * 5 + ky) * 5 + kx] : 0.f;
        v[j] = f2b(f);
    }
    uint4 u;
    u.x = (uint)v[0] | ((uint)v[1] << 16);
    u.y = (uint)v[2] | ((uint)v[3] << 16);
    u.z = (uint)v[4] | ((uint)v[5] << 16);
    u.w = (uint)v[6] | ((uint)v[7] << 16);
    o[i] = u;
}

// ============ conv1: [128][164][328][4] -> [128][84][164][16], 5 ksteps (ky) ============
__global__ __launch_bounds__(256) void conv1_mfma(const ushort* __restrict__ inp,
                                                  const uint4* __restrict__ wswz,
                                                  const float* __restrict__ bias,
                                                  ushort* __restrict__ outp) {
    const int lane = threadIdx.x & 63;
    const int wid = threadIdx.x >> 6;
    const int col = lane & 15, q = lane >> 4;

    Frag A[5];
#pragma unroll
    for (int s = 0; s < 5; s++) A[s].u = wswz[s * 64 + lane];
    float b0 = bias[q * 4 + 0], b1 = bias[q * 4 + 1], b2 = bias[q * 4 + 2], b3 = bias[q * 4 + 3];

    int gw = blockIdx.x * 4 + wid;
#pragma unroll
    for (int t = 0; t < 4; t++) {
        int p0 = gw * 64 + t * 16;
        int n = p0 / 12800;
        int rem = p0 - n * 12800;
        int oy = rem / 160;
        int ox0 = rem - oy * 160;  // OW=160 multiple of 16: no row-cross
        int ox = ox0 + col;
        uint e0 = ((uint)(n * 164 + oy * 2) * 328u + (uint)(ox * 2 + 2 * q)) * 4u;
        f32x4 acc = {0.f, 0.f, 0.f, 0.f};
#pragma unroll
        for (int s = 0; s < 5; s++) {
            Frag B;
            B.u = *(const uint4*)(inp + e0 + (uint)s * (328u * 4u));
            acc = __builtin_amdgcn_mfma_f32_16x16x32_bf16(A[s].s, B.s, acc, 0, 0, 0);
        }
        uint oe = ((uint)(n * 84 + oy + 2) * 164u + (uint)(ox + 2)) * 16u + q * 4u;
        uint2 pk;
        pk.x = (uint)f2b(fmaxf(acc[0] + b0, 0.f)) | ((uint)f2b(fmaxf(acc[1] + b1, 0.f)) << 16);
        pk.y = (uint)f2b(fmaxf(acc[2] + b2, 0.f)) | ((uint)f2b(fmaxf(acc[3] + b3, 0.f)) << 16);
        *(uint2*)(outp + oe) = pk;
    }
}

// ============ conv2: [128][84][164][16] -> [128][44][84][32], 15 ksteps ============
__global__ __launch_bounds__(256) void conv2_mfma(const ushort* __restrict__ inp,
                                                  const uint4* __restrict__ wswz,
                                                  const float* __restrict__ bias,
                                                  ushort* __restrict__ outp) {
    const int lane = threadIdx.x & 63;
    const int wid = threadIdx.x >> 6;
    const int col = lane & 15, q = lane >> 4;
    const int h = q >> 1, chh = q & 1;

    int gw = blockIdx.x * 4 + wid;
    uint eb[4];
#pragma unroll
    for (int t = 0; t < 4; t++) {
        int p0 = gw * 64 + t * 16;
        int n = p0 / 3200;
        int rem = p0 - n * 3200;
        int oy = rem / 80;
        int ox0 = rem - oy * 80;  // OW=80 multiple of 16: no row-cross
        eb[t] = ((uint)(n * 84 + oy * 2) * 164u + (uint)((ox0 + col) * 2 + h)) * 16u + chh * 8u;
    }
    f32x4 acc[4][2];
#pragma unroll
    for (int t = 0; t < 4; t++) {
        acc[t][0] = {0.f, 0.f, 0.f, 0.f};
        acc[t][1] = {0.f, 0.f, 0.f, 0.f};
    }
#pragma unroll
    for (int s = 0; s < 15; s++) {
        const int ky = s / 3, kxp = s % 3;
        Frag A0, A1;
        A0.u = wswz[(s * 2 + 0) * 64 + lane];
        A1.u = wswz[(s * 2 + 1) * 64 + lane];
        const uint d = (uint)ky * (164u * 16u) + (uint)kxp * 32u;
#pragma unroll
        for (int t = 0; t < 4; t++) {
            Frag B;
            B.u = *(const uint4*)(inp + eb[t] + d);
            acc[t][0] = __builtin_amdgcn_mfma_f32_16x16x32_bf16(A0.s, B.s, acc[t][0], 0, 0, 0);
            acc[t][1] = __builtin_amdgcn_mfma_f32_16x16x32_bf16(A1.s, B.s, acc[t][1], 0, 0, 0);
        }
    }
    float ba[2][4];
#pragma unroll
    for (int c = 0; c < 2; c++)
#pragma unroll
        for (int r = 0; r < 4; r++) ba[c][r] = bias[c * 16 + q * 4 + r];
#pragma unroll
    for (int t = 0; t < 4; t++) {
        int p0 = gw * 64 + t * 16;
        int n = p0 / 3200;
        int rem = p0 - n * 3200;
        int oy = rem / 80;
        int ox0 = rem - oy * 80;
        int ox = ox0 + col;
        uint oe = ((uint)(n * 44 + oy + 2) * 84u + (uint)(ox + 2)) * 32u;
#pragma unroll
        for (int c = 0; c < 2; c++) {
            uint2 pk;
            pk.x = (uint)f2b(fmaxf(acc[t][c][0] + ba[c][0], 0.f)) |
                   ((uint)f2b(fmaxf(acc[t][c][1] + ba[c][1], 0.f)) << 16);
            pk.y = (uint)f2b(fmaxf(acc[t][c][2] + ba[c][2], 0.f)) |
                   ((uint)f2b(fmaxf(acc[t][c][3] + ba[c][3], 0.f)) << 16);
            *(uint2*)(outp + oe + (uint)c * 16u + (uint)q * 4u) = pk;
        }
    }
}

// ============ conv3: [128][44][84][32] -> [128][800][8] f32 (NHWC), 25 ksteps ============
__global__ __launch_bounds__(256) void conv3_mfma(const ushort* __restrict__ inp,
                                                  const uint4* __restrict__ wswz,
                                                  const float* __restrict__ bias,
                                                  float* __restrict__ outp) {
    const int lane = threadIdx.x & 63;
    const int wid = threadIdx.x >> 6;
    const int col = lane & 15, q = lane >> 4;

    int gw = blockIdx.x * 4 + wid;
    uint eb[4];
#pragma unroll
    for (int t = 0; t < 4; t++) {
        int p0 = gw * 64 + t * 16;
        int n = p0 / 800;
        // OW=40 not a multiple of 16: per-lane pixel coords (row-wrap safe)
        int pix = p0 - n * 800 + col;
        int oy = pix / 40;
        int ox = pix - oy * 40;
        eb[t] = ((uint)(n * 44 + oy * 2) * 84u + (uint)(ox * 2)) * 32u + q * 8u;
    }
    f32x4 acc[4];
#pragma unroll
    for (int t = 0; t < 4; t++) acc[t] = {0.f, 0.f, 0.f, 0.f};
#pragma unroll
    for (int s = 0; s < 25; s++) {
        const int ky = s / 5, kx = s % 5;
        Frag A;
        A.u = wswz[s * 64 + lane];
        const uint d = ((uint)ky * 84u + (uint)kx) * 32u;
#pragma unroll
        for (int t = 0; t < 4; t++) {
            Frag B;
            B.u = *(const uint4*)(inp + eb[t] + d);
            acc[t] = __builtin_amdgcn_mfma_f32_16x16x32_bf16(A.s, B.s, acc[t], 0, 0, 0);
        }
    }
    if (q < 2) {
        float b0 = bias[q * 4 + 0], b1 = bias[q * 4 + 1];
        float b2 = bias[q * 4 + 2], b3 = bias[q * 4 + 3];
#pragma unroll
        for (int t = 0; t < 4; t++) {
            int p0 = gw * 64 + t * 16;
            int n = p0 / 800;
            int p = p0 - n * 800 + col;
            float4 v;
            v.x = fmaxf(acc[t][0] + b0, 0.f);
            v.y = fmaxf(acc[t][1] + b1, 0.f);
            v.z = fmaxf(acc[t][2] + b2, 0.f);
            v.w = fmaxf(acc[t][3] + b3, 0.f);
            *(float4*)(outp + ((size_t)n * 800 + p) * 8 + q * 4) = v;
        }
    }
}

// ============ head ============
__global__ void head_kernel(const float* __restrict__ x, const float* __restrict__ hw,
                            const float* __restrict__ hb, float* __restrict__ feats) {
    int n = blockIdx.x;
    int tid = threadIdx.x;  // 0..63
    int f = tid >> 3;
    int k = tid & 7;
    const float* xb = x + (size_t)n * 800 * 8 + f;
    const float* wb = hw + ((size_t)f * 800) * FPF + k;
    float acc = hb[tid];
    for (int p = 0; p < 800; p++) acc = fmaf(xb[(size_t)p * 8], wb[(size_t)p * FPF], acc);
    feats[n * 64 + tid] = acc;
}

// ============ global std (ddof=1) ============
__global__ void stats_kernel(const float* __restrict__ feats, float* __restrict__ invstd) {
    __shared__ float s_sum[256], s_sq[256];
    int tid = threadIdx.x;
    float s = 0.0f, q = 0.0f;
    for (int i = tid; i < 8192; i += 256) {
        float x = feats[i];
        s += x;
        q += x * x;
    }
    s_sum[tid] = s;
    s_sq[tid] = q;
    __syncthreads();
    for (int off = 128; off > 0; off >>= 1) {
        if (tid < off) {
            s_sum[tid] += s_sum[tid + off];
            s_sq[tid] += s_sq[tid + off];
        }
        __syncthreads();
    }
    if (tid == 0) {
        float mean = s_sum[0] / 8192.0f;
        float var = (s_sq[0] - 8192.0f * mean * mean) / 8191.0f;
        var = fmaxf(var, 0.0f);
        invstd[0] = 1.0f / (sqrtf(var) + 1e-5f);
    }
}

// ============ speed embedding ============
__global__ void semb_kernel(const float* __restrict__ speed, const float* __restrict__ w1,
                            const float* __restrict__ b1, const float* __restrict__ w2,
                            const float* __restrict__ b2, float* __restrict__ emb) {
    int n = threadIdx.x;  // 0..127
    float s = speed[n];
    float h[16];
#pragma unroll
    for (int j = 0; j < 16; j++) h[j] = fmaxf(fmaf(s, w1[j], b1[j]), 0.0f);
#pragma unroll
    for (int k = 0; k < SDIM; k++) {
        float a = b2[k];
#pragma unroll
        for (int j = 0; j < 16; j++) a = fmaf(h[j], w2[j * SDIM + k], a);
        emb[n * SDIM + k] = tanhf(a);
    }
}

// ============ sensory precompute ============
__global__ void sensory_kernel(const float* __restrict__ feats, const float* __restrict__ emb,
                               const float* __restrict__ invstd, const float* __restrict__ inw,
                               const float* __restrict__ inb, const float* __restrict__ ssig,
                               const float* __restrict__ smu, const float* __restrict__ sw,
                               const float* __restrict__ serev, float* __restrict__ wns,
                               float* __restrict__ wds) {
    int bid = blockIdx.x;  // t*4 + b
    int t = bid >> 2;
    int b = bid & 3;
    int u = threadIdx.x;  // 0..63
    int n = b * TT + t;
    float inv = invstd[0];
    float num = 0.0f, den = 0.0f;
    for (int s = 0; s < SS; s++) {
        float xsv = (s < 64) ? feats[n * 64 + s] * inv : emb[n * SDIM + (s - 64)];
        float inp = fmaf(xsv, inw[s], inb[s]);
        int idx = s * UU + u;
        float x = (inp - smu[idx]) * ssig[idx];
        float act = sw[idx] * fast_sigmoid(x);
        num = fmaf(act, serev[idx], num);
        den += act;
    }
    wns[bid * UU + u] = num;
    wds[bid * UU + u] = den;
}

// ============ LTC scan v2: replicated-v + readlane broadcast + 1 barrier/unfold ============
// 4 blocks (one per batch), 256 threads = wave pc handles pre-chunk pc; every
// wave redundantly maintains the full v vector (lane u <-> v_u).
__global__ __launch_bounds__(256) void scan_kernel(
    const float* __restrict__ wns, const float* __restrict__ wds,
    const float* __restrict__ gleak, const float* __restrict__ vleak,
    const float* __restrict__ cm, const float* __restrict__ sigma,
    const float* __restrict__ mu, const float* __restrict__ wsyn,
    const float* __restrict__ erev, const float* __restrict__ outw,
    const float* __restrict__ outb, float* __restrict__ dout) {
    int b = blockIdx.x;
    int tid = threadIdx.x;
    int u = tid & 63;
    int pc = tid >> 6;

    // [parity][pc][u] -> (num, den); double-buffered so ONE barrier per unfold
    __shared__ float2 pbuf[2][4][64];

    // strength-reduced synapse params for this thread's 16 pre rows:
    // arg = -log2e * (v - mu) * sigma = fma(v, sA, sB)
    float sA[16], sB[16], wer[16], w_[16];
#pragma unroll
    for (int i = 0; i < 16; i++) {
        int idx = (pc * 16 + i) * UU + u;
        float sg = sigma[idx];
        sA[i] = -1.44269504f * sg;
        sB[i] = -sA[i] * mu[idx];
        w_[i] = wsyn[idx];
        wer[i] = w_[i] * erev[idx];
    }
    float cmt = cm[u] * (float)UNFOLDS;
    float gl = gleak[u];
    float glvl = gl * vleak[u];
    float ow = outw[0], ob = outb[0];
    float v = 0.0f;
    int par = 0;

    for (int t = 0; t < TT; t++) {
        float num_s = wns[(t * BB + b) * UU + u];
        float den_s = wds[(t * BB + b) * UU + u];
#pragma unroll
        for (int k = 0; k < UNFOLDS; k++) {
            float num = 0.0f, den = 0.0f;
#pragma unroll
            for (int i = 0; i < 16; i++) {
                float vi = bcast_lane(v, pc * 16 + i);  // v_readlane -> SGPR
                float e = exp2f(fmaf(vi, sA[i], sB[i]));
                float r = __builtin_amdgcn_rcpf(1.0f + e);
                num = fmaf(wer[i], r, num);
                den = fmaf(w_[i], r, den);
            }
            pbuf[par][pc][u] = make_float2(num, den);
            __syncthreads();
            float2 p0 = pbuf[par][0][u];
            float2 p1 = pbuf[par][1][u];
            float2 p2 = pbuf[par][2][u];
            float2 p3 = pbuf[par][3][u];
            float nn = p0.x + p1.x + p2.x + p3.x + num_s;
            float dd = p0.y + p1.y + p2.y + p3.y + den_s;
            float denom = cmt + gl + dd + 1e-8f;
            v = (fmaf(cmt, v, glvl) + nn) * __builtin_amdgcn_rcpf(denom);
            par ^= 1;
        }
        if (pc == 0) {
            dout[384 + (b * TT + t) * UU + u] = v;
            if (u == 0) dout[b * TT + t] = fmaf(v, ow, ob);
            if (t == TT - 1) dout[128 + b * UU + u] = v;
        }
    }
}

extern "C" void kernel_launch(void* const* d_in, const int* in_sizes, int n_in,
                              void* d_out, int out_size, void* d_ws, size_t ws_size,
                              hipStream_t stream) {
    const float* in_seq = (const float*)d_in[0];
    const float* speed = (const float*)d_in[1];
    const float* c1w = (const float*)d_in[2];
    const float* c1b = (const float*)d_in[3];
    const float* c2w = (const float*)d_in[4];
    const float* c2b = (const float*)d_in[5];
    const float* c3w = (const float*)d_in[6];
    const float* c3b = (const float*)d_in[7];
    const float* hw = (const float*)d_in[8];
    const float* hb = (const float*)d_in[9];
    const float* sew1 = (const float*)d_in[10];
    const float* seb1 = (const float*)d_in[11];
    const float* sew2 = (const float*)d_in[12];
    const float* seb2 = (const float*)d_in[13];
    const float* inw = (const float*)d_in[14];
    const float* inb = (const float*)d_in[15];
    const float* gleak = (const float*)d_in[16];
    const float* vleak = (const float*)d_in[17];
    const float* cm = (const float*)d_in[18];
    const float* sigma = (const float*)d_in[19];
    const float* mu = (const float*)d_in[20];
    const float* wsyn = (const float*)d_in[21];
    const float* erev = (const float*)d_in[22];
    const float* ssig = (const float*)d_in[23];
    const float* smu = (const float*)d_in[24];
    const float* sw = (const float*)d_in[25];
    const float* serev = (const float*)d_in[26];
    const float* outw = (const float*)d_in[27];
    const float* outb = (const float*)d_in[28];

    char* ws = (char*)d_ws;
    float* out = (float*)d_out;

    size_t off = 0;
    auto alloc = [&](size_t bytes) {
        size_t o = off;
        off += (bytes + 255) & ~(size_t)255;
        return o;
    };
    ushort* inp1 = (ushort*)(ws + alloc((size_t)128 * 164 * 328 * 4 * 2));
    ushort* c1out = (ushort*)(ws + alloc((size_t)128 * 84 * 164 * 16 * 2));
    ushort* c2out = (ushort*)(ws + alloc((size_t)128 * 44 * 84 * 32 * 2));
    float* c3out = (float*)(ws + alloc((size_t)128 * 800 * 8 * 4));
    float* feats = (float*)(ws + alloc(8192 * 4));
    float* emb = (float*)(ws + alloc(1024 * 4));
    float* invstd = (float*)(ws + alloc(64));
    float* wns = (float*)(ws + alloc(8192 * 4));
    float* wds = (float*)(ws + alloc(8192 * 4));
    uint4* wz1 = (uint4*)(ws + alloc(5 * 64 * 16));
    uint4* wz2 = (uint4*)(ws + alloc(30 * 64 * 16));
    uint4* wz3 = (uint4*)(ws + alloc(25 * 64 * 16));

    // weight swizzles
    wswz1_kernel<<<5, 64, 0, stream>>>(c1w, wz1);
    wswz2_kernel<<<30, 64, 0, stream>>>(c2w, wz2);
    wswz3_kernel<<<25, 64, 0, stream>>>(c3w, wz3);

    // halo fills (halo-only grids) + input conversion
    fill_halo<164, 328, 160, 320, 4><<<1296, 256, 0, stream>>>(inp1);
    fill_halo<84, 164, 80, 160, 16><<<488, 256, 0, stream>>>(c1out);
    fill_halo<44, 84, 40, 80, 32><<<248, 256, 0, stream>>>(c2out);
    cvt_input<<<25600, 256, 0, stream>>>(in_seq, inp1);

    // MFMA convs
    conv1_mfma<<<6400, 256, 0, stream>>>(inp1, wz1, c1b, c1out);
    conv2_mfma<<<1600, 256, 0, stream>>>(c1out, wz2, c2b, c2out);
    conv3_mfma<<<400, 256, 0, stream>>>(c2out, wz3, c3b, c3out);

    // head + stats + speed embedding
    head_kernel<<<128, 64, 0, stream>>>(c3out, hw, hb, feats);
    stats_kernel<<<1, 256, 0, stream>>>(feats, invstd);
    semb_kernel<<<1, 128, 0, stream>>>(speed, sew1, seb1, sew2, seb2, emb);

    // sensory precompute
    sensory_kernel<<<TT * BB, 64, 0, stream>>>(feats, emb, invstd, inw, inb, ssig, smu, sw,
                                               serev, wns, wds);

    // serial LTC scan
    scan_kernel<<<BB, 256, 0, stream>>>(wns, wds, gleak, vleak, cm, sigma, mu, wsyn, erev,
                                        outw, outb, out);
}

// Round 6
// 279.134 us; speedup vs baseline: 3.5806x; 1.0512x over previous
//
#include <hip/hip_runtime.h>
#include <math.h>

// Problem constants
#define BB 4
#define TT 32
#define NF 8
#define FPF 8
#define SDIM 8
#define UU 64
#define SS 72
#define UNFOLDS 6

typedef short short8 __attribute__((ext_vector_type(8)));
typedef float f32x4 __attribute__((ext_vector_type(4)));
union Frag { uint4 u; short8 s; };

__device__ __forceinline__ float fast_sigmoid(float x) {
    float e = exp2f(-1.44269504f * x);
    return __builtin_amdgcn_rcpf(1.0f + e);
}

// fp32 -> bf16 bits, round-to-nearest-even (inputs finite)
__device__ __forceinline__ ushort f2b(float f) {
    union { float f; uint u; } a;
    a.f = f;
    uint u = a.u;
    return (ushort)((u + 0x7FFFu + ((u >> 16) & 1u)) >> 16);
}

__device__ __forceinline__ float bcast_lane(float v, int lane) {
    return __uint_as_float(__builtin_amdgcn_readlane(__float_as_uint(v), lane));
}

// ============ input f32 NCHW -> padded NHWC bf16 [128][164][328][4] (c3=0) ============
__global__ __launch_bounds__(256) void cvt_input(const float* __restrict__ in,
                                                 ushort* __restrict__ outp) {
    int idx = blockIdx.x * 256 + threadIdx.x;
    if (idx >= 128 * 160 * 320) return;
    int x = idx % 320;
    int r = idx / 320;
    int y = r % 160;
    int n = r / 160;
    const float* base = in + ((size_t)n * 3 * 160 + y) * 320 + x;
    float c0 = base[0];
    float c1 = base[160 * 320];
    float c2 = base[2 * 160 * 320];
    uint2 pk;
    pk.x = (uint)f2b(c0) | ((uint)f2b(c1) << 16);
    pk.y = (uint)f2b(c2);
    *(uint2*)(outp + ((size_t)((n * 164 + y + 2) * 328) + (x + 2)) * 4) = pk;
}

// ============ halo zero fill (halo-cells-only enumeration) ============
template <int HP, int WP, int H, int W, int CH>
__global__ __launch_bounds__(256) void fill_halo(ushort* __restrict__ buf) {
    constexpr int TOPBOT = 2 * WP;
    constexpr int SIDE = WP - W;
    constexpr int NH = 2 * TOPBOT + H * SIDE;
    int idx = blockIdx.x * 256 + threadIdx.x;
    if (idx >= 128 * NH) return;
    int n = idx / NH;
    int h = idx - n * NH;
    int y, x;
    if (h < TOPBOT) {
        y = h / WP;
        x = h % WP;
    } else if (h < 2 * TOPBOT) {
        int hh = h - TOPBOT;
        y = H + 2 + hh / WP;
        x = hh % WP;
    } else {
        int hh = h - 2 * TOPBOT;
        y = 2 + hh / SIDE;
        int xi = hh % SIDE;
        x = (xi < 2) ? xi : (W + xi);
    }
    ushort* p = buf + (((size_t)n * HP + y) * WP + x) * CH;
    if constexpr (CH == 4) {
        *(uint2*)p = make_uint2(0u, 0u);
    } else {
        uint4 z = make_uint4(0u, 0u, 0u, 0u);
#pragma unroll
        for (int i = 0; i < CH / 8; i++) *(uint4*)(p + i * 8) = z;
    }
}

// ============ weight swizzles into MFMA A-fragment layout ============
__global__ void wswz1_kernel(const float* __restrict__ w, uint4* __restrict__ o) {
    int i = blockIdx.x * 64 + threadIdx.x;  // [5 ky][64 lanes]
    if (i >= 5 * 64) return;
    int lane = i & 63, s = i >> 6;
    int oc = lane & 15, q = lane >> 4;
    ushort v[8];
#pragma unroll
    for (int j = 0; j < 8; j++) {
        int k = q * 8 + j;
        int kx = k >> 2, c = k & 3;
        float f = (kx < 5 && c < 3) ? w[((oc * 3 + c) * 5 + s) * 5 + kx] : 0.f;
        v[j] = f2b(f);
    }
    uint4 u;
    u.x = (uint)v[0] | ((uint)v[1] << 16);
    u.y = (uint)v[2] | ((uint)v[3] << 16);
    u.z = (uint)v[4] | ((uint)v[5] << 16);
    u.w = (uint)v[6] | ((uint)v[7] << 16);
    o[i] = u;
}
__global__ void wswz2_kernel(const float* __restrict__ w, uint4* __restrict__ o) {
    int i = blockIdx.x * 64 + threadIdx.x;  // [15 kstep][2 octile][64]
    if (i >= 15 * 2 * 64) return;
    int lane = i & 63;
    int ct = (i >> 6) & 1;
    int s = i >> 7;
    int ky = s / 3, kxp = s % 3;
    int oc = ct * 16 + (lane & 15);
    int q = lane >> 4, h = q >> 1;
    int kx = 2 * kxp + h;
    ushort v[8];
#pragma unroll
    for (int j = 0; j < 8; j++) {
        int ch = (q & 1) * 8 + j;
        float f = (kx < 5) ? w[((oc * 16 + ch) * 5 + ky) * 5 + kx] : 0.f;
        v[j] = f2b(f);
    }
    uint4 u;
    u.x = (uint)v[0] | ((uint)v[1] << 16);
    u.y = (uint)v[2] | ((uint)v[3] << 16);
    u.z = (uint)v[4] | ((uint)v[5] << 16);
    u.w = (uint)v[6] | ((uint)v[7] << 16);
    o[i] = u;
}
__global__ void wswz3_kernel(const float* __restrict__ w, uint4* __restrict__ o) {
    int i = blockIdx.x * 64 + threadIdx.x;  // [25 tap][64]
    if (i >= 25 * 64) return;
    int lane = i & 63, s = i >> 6;
    int ky = s / 5, kx = s % 5;
    int oc = lane & 15, q = lane >> 4;
    ushort v[8];
#pragma unroll
    for (int j = 0; j < 8; j++) {
        int ch = q * 8 + j;
        float f = (oc < 8) ? w[((oc * 32 + ch) * 5 + ky) * 5 + kx] : 0.f;
        v[j] = f2b(f);
    }
    uint4 u;
    u.x = (uint)v[0] | ((uint)v[1] << 16);
    u.y = (uint)v[2] | ((uint)v[3] << 16);
    u.z = (uint)v[4] | ((uint)v[5] << 16);
    u.w = (uint)v[6] | ((uint)v[7] << 16);
    o[i] = u;
}

// ============ conv1: [128][164][328][4] -> [128][84][164][16], 5 ksteps (ky) ============
__global__ __launch_bounds__(256) void conv1_mfma(const ushort* __restrict__ inp,
                                                  const uint4* __restrict__ wswz,
                                                  const float* __restrict__ bias,
                                                  ushort* __restrict__ outp) {
    const int lane = threadIdx.x & 63;
    const int wid = threadIdx.x >> 6;
    const int col = lane & 15, q = lane >> 4;

    Frag A[5];
#pragma unroll
    for (int s = 0; s < 5; s++) A[s].u = wswz[s * 64 + lane];
    float b0 = bias[q * 4 + 0], b1 = bias[q * 4 + 1], b2 = bias[q * 4 + 2], b3 = bias[q * 4 + 3];

    int gw = blockIdx.x * 4 + wid;
#pragma unroll
    for (int t = 0; t < 4; t++) {
        int p0 = gw * 64 + t * 16;
        int n = p0 / 12800;
        int rem = p0 - n * 12800;
        int oy = rem / 160;
        int ox0 = rem - oy * 160;
        int ox = ox0 + col;
        uint e0 = ((uint)(n * 164 + oy * 2) * 328u + (uint)(ox * 2 + 2 * q)) * 4u;
        f32x4 acc = {0.f, 0.f, 0.f, 0.f};
#pragma unroll
        for (int s = 0; s < 5; s++) {
            Frag B;
            B.u = *(const uint4*)(inp + e0 + (uint)s * (328u * 4u));
            acc = __builtin_amdgcn_mfma_f32_16x16x32_bf16(A[s].s, B.s, acc, 0, 0, 0);
        }
        uint oe = ((uint)(n * 84 + oy + 2) * 164u + (uint)(ox + 2)) * 16u + q * 4u;
        uint2 pk;
        pk.x = (uint)f2b(fmaxf(acc[0] + b0, 0.f)) | ((uint)f2b(fmaxf(acc[1] + b1, 0.f)) << 16);
        pk.y = (uint)f2b(fmaxf(acc[2] + b2, 0.f)) | ((uint)f2b(fmaxf(acc[3] + b3, 0.f)) << 16);
        *(uint2*)(outp + oe) = pk;
    }
}

// ============ conv2: [128][84][164][16] -> [128][44][84][32], 15 ksteps ============
__global__ __launch_bounds__(256) void conv2_mfma(const ushort* __restrict__ inp,
                                                  const uint4* __restrict__ wswz,
                                                  const float* __restrict__ bias,
                                                  ushort* __restrict__ outp) {
    const int lane = threadIdx.x & 63;
    const int wid = threadIdx.x >> 6;
    const int col = lane & 15, q = lane >> 4;
    const int h = q >> 1, chh = q & 1;

    int gw = blockIdx.x * 4 + wid;
    uint eb[4];
#pragma unroll
    for (int t = 0; t < 4; t++) {
        int p0 = gw * 64 + t * 16;
        int n = p0 / 3200;
        int rem = p0 - n * 3200;
        int oy = rem / 80;
        int ox0 = rem - oy * 80;
        eb[t] = ((uint)(n * 84 + oy * 2) * 164u + (uint)((ox0 + col) * 2 + h)) * 16u + chh * 8u;
    }
    f32x4 acc[4][2];
#pragma unroll
    for (int t = 0; t < 4; t++) {
        acc[t][0] = {0.f, 0.f, 0.f, 0.f};
        acc[t][1] = {0.f, 0.f, 0.f, 0.f};
    }
#pragma unroll
    for (int s = 0; s < 15; s++) {
        const int ky = s / 3, kxp = s % 3;
        Frag A0, A1;
        A0.u = wswz[(s * 2 + 0) * 64 + lane];
        A1.u = wswz[(s * 2 + 1) * 64 + lane];
        const uint d = (uint)ky * (164u * 16u) + (uint)kxp * 32u;
#pragma unroll
        for (int t = 0; t < 4; t++) {
            Frag B;
            B.u = *(const uint4*)(inp + eb[t] + d);
            acc[t][0] = __builtin_amdgcn_mfma_f32_16x16x32_bf16(A0.s, B.s, acc[t][0], 0, 0, 0);
            acc[t][1] = __builtin_amdgcn_mfma_f32_16x16x32_bf16(A1.s, B.s, acc[t][1], 0, 0, 0);
        }
    }
    float ba[2][4];
#pragma unroll
    for (int c = 0; c < 2; c++)
#pragma unroll
        for (int r = 0; r < 4; r++) ba[c][r] = bias[c * 16 + q * 4 + r];
#pragma unroll
    for (int t = 0; t < 4; t++) {
        int p0 = gw * 64 + t * 16;
        int n = p0 / 3200;
        int rem = p0 - n * 3200;
        int oy = rem / 80;
        int ox0 = rem - oy * 80;
        int ox = ox0 + col;
        uint oe = ((uint)(n * 44 + oy + 2) * 84u + (uint)(ox + 2)) * 32u;
#pragma unroll
        for (int c = 0; c < 2; c++) {
            uint2 pk;
            pk.x = (uint)f2b(fmaxf(acc[t][c][0] + ba[c][0], 0.f)) |
                   ((uint)f2b(fmaxf(acc[t][c][1] + ba[c][1], 0.f)) << 16);
            pk.y = (uint)f2b(fmaxf(acc[t][c][2] + ba[c][2], 0.f)) |
                   ((uint)f2b(fmaxf(acc[t][c][3] + ba[c][3], 0.f)) << 16);
            *(uint2*)(outp + oe + (uint)c * 16u + (uint)q * 4u) = pk;
        }
    }
}

// ============ conv3: [128][44][84][32] -> [128][800][8] f32 (NHWC), 25 ksteps ============
__global__ __launch_bounds__(256) void conv3_mfma(const ushort* __restrict__ inp,
                                                  const uint4* __restrict__ wswz,
                                                  const float* __restrict__ bias,
                                                  float* __restrict__ outp) {
    const int lane = threadIdx.x & 63;
    const int wid = threadIdx.x >> 6;
    const int col = lane & 15, q = lane >> 4;

    int gw = blockIdx.x * 4 + wid;
    uint eb[4];
#pragma unroll
    for (int t = 0; t < 4; t++) {
        int p0 = gw * 64 + t * 16;
        int n = p0 / 800;
        int pix = p0 - n * 800 + col;  // per-lane coords (row-wrap safe, OW=40)
        int oy = pix / 40;
        int ox = pix - oy * 40;
        eb[t] = ((uint)(n * 44 + oy * 2) * 84u + (uint)(ox * 2)) * 32u + q * 8u;
    }
    f32x4 acc[4];
#pragma unroll
    for (int t = 0; t < 4; t++) acc[t] = {0.f, 0.f, 0.f, 0.f};
#pragma unroll
    for (int s = 0; s < 25; s++) {
        const int ky = s / 5, kx = s % 5;
        Frag A;
        A.u = wswz[s * 64 + lane];
        const uint d = ((uint)ky * 84u + (uint)kx) * 32u;
#pragma unroll
        for (int t = 0; t < 4; t++) {
            Frag B;
            B.u = *(const uint4*)(inp + eb[t] + d);
            acc[t] = __builtin_amdgcn_mfma_f32_16x16x32_bf16(A.s, B.s, acc[t], 0, 0, 0);
        }
    }
    if (q < 2) {
        float b0 = bias[q * 4 + 0], b1 = bias[q * 4 + 1];
        float b2 = bias[q * 4 + 2], b3 = bias[q * 4 + 3];
#pragma unroll
        for (int t = 0; t < 4; t++) {
            int p0 = gw * 64 + t * 16;
            int n = p0 / 800;
            int p = p0 - n * 800 + col;
            float4 v;
            v.x = fmaxf(acc[t][0] + b0, 0.f);
            v.y = fmaxf(acc[t][1] + b1, 0.f);
            v.z = fmaxf(acc[t][2] + b2, 0.f);
            v.w = fmaxf(acc[t][3] + b3, 0.f);
            *(float4*)(outp + ((size_t)n * 800 + p) * 8 + q * 4) = v;
        }
    }
}

// ============ head: 256 threads, 4-way p-split + LDS reduce ============
__global__ __launch_bounds__(256) void head_kernel(const float* __restrict__ x,
                                                   const float* __restrict__ hw,
                                                   const float* __restrict__ hb,
                                                   float* __restrict__ feats) {
    __shared__ float part[4][64];
    int n = blockIdx.x;
    int tid = threadIdx.x;
    int lane = tid & 63;
    int c = tid >> 6;  // p-chunk 0..3
    int f = lane >> 3;
    int k = lane & 7;
    const float* xb = x + (size_t)n * 800 * 8 + f;
    const float* wb = hw + ((size_t)f * 800) * FPF + k;
    float acc = 0.0f;
    for (int p = c * 200; p < c * 200 + 200; p++)
        acc = fmaf(xb[(size_t)p * 8], wb[(size_t)p * FPF], acc);
    part[c][lane] = acc;
    __syncthreads();
    if (c == 0)
        feats[n * 64 + lane] = part[0][lane] + part[1][lane] + part[2][lane] + part[3][lane] +
                               hb[lane];
}

// ============ global std (ddof=1) ============
__global__ void stats_kernel(const float* __restrict__ feats, float* __restrict__ invstd) {
    __shared__ float s_sum[256], s_sq[256];
    int tid = threadIdx.x;
    float s = 0.0f, q = 0.0f;
    for (int i = tid; i < 8192; i += 256) {
        float x = feats[i];
        s += x;
        q += x * x;
    }
    s_sum[tid] = s;
    s_sq[tid] = q;
    __syncthreads();
    for (int off = 128; off > 0; off >>= 1) {
        if (tid < off) {
            s_sum[tid] += s_sum[tid + off];
            s_sq[tid] += s_sq[tid + off];
        }
        __syncthreads();
    }
    if (tid == 0) {
        float mean = s_sum[0] / 8192.0f;
        float var = (s_sq[0] - 8192.0f * mean * mean) / 8191.0f;
        var = fmaxf(var, 0.0f);
        invstd[0] = 1.0f / (sqrtf(var) + 1e-5f);
    }
}

// ============ speed embedding ============
__global__ void semb_kernel(const float* __restrict__ speed, const float* __restrict__ w1,
                            const float* __restrict__ b1, const float* __restrict__ w2,
                            const float* __restrict__ b2, float* __restrict__ emb) {
    int n = threadIdx.x;  // 0..127
    float s = speed[n];
    float h[16];
#pragma unroll
    for (int j = 0; j < 16; j++) h[j] = fmaxf(fmaf(s, w1[j], b1[j]), 0.0f);
#pragma unroll
    for (int k = 0; k < SDIM; k++) {
        float a = b2[k];
#pragma unroll
        for (int j = 0; j < 16; j++) a = fmaf(h[j], w2[j * SDIM + k], a);
        emb[n * SDIM + k] = tanhf(a);
    }
}

// ============ sensory precompute ============
__global__ void sensory_kernel(const float* __restrict__ feats, const float* __restrict__ emb,
                               const float* __restrict__ invstd, const float* __restrict__ inw,
                               const float* __restrict__ inb, const float* __restrict__ ssig,
                               const float* __restrict__ smu, const float* __restrict__ sw,
                               const float* __restrict__ serev, float* __restrict__ wns,
                               float* __restrict__ wds) {
    int bid = blockIdx.x;  // t*4 + b
    int t = bid >> 2;
    int b = bid & 3;
    int u = threadIdx.x;  // 0..63
    int n = b * TT + t;
    float inv = invstd[0];
    float num = 0.0f, den = 0.0f;
    for (int s = 0; s < SS; s++) {
        float xsv = (s < 64) ? feats[n * 64 + s] * inv : emb[n * SDIM + (s - 64)];
        float inp = fmaf(xsv, inw[s], inb[s]);
        int idx = s * UU + u;
        float x = (inp - smu[idx]) * ssig[idx];
        float act = sw[idx] * fast_sigmoid(x);
        num = fmaf(act, serev[idx], num);
        den += act;
    }
    wns[bid * UU + u] = num;
    wds[bid * UU + u] = den;
}

// ============ LTC scan v3: params pinned in VGPRs via asm launder ============
// 4 blocks (one per batch), 256 threads; launch_bounds(256,1) gives the
// allocator the full 512-VGPR budget so the 64 param values stay resident.
__global__ __launch_bounds__(256, 1) void scan_kernel(
    const float* __restrict__ wns, const float* __restrict__ wds,
    const float* __restrict__ gleak, const float* __restrict__ vleak,
    const float* __restrict__ cm, const float* __restrict__ sigma,
    const float* __restrict__ mu, const float* __restrict__ wsyn,
    const float* __restrict__ erev, const float* __restrict__ outw,
    const float* __restrict__ outb, float* __restrict__ dout) {
    int b = blockIdx.x;
    int tid = threadIdx.x;
    int u = tid & 63;
    int pc = tid >> 6;

    __shared__ float2 pbuf[2][4][64];

    // strength-reduced synapse params: arg = fma(v, sA, sB); act = w * sigmoid
    float sA[16], sB[16], wer[16], w_[16];
#pragma unroll
    for (int i = 0; i < 16; i++) {
        int idx = (pc * 16 + i) * UU + u;
        float sg = sigma[idx];
        sA[i] = -1.44269504f * sg;
        sB[i] = -sA[i] * mu[idx];
        w_[i] = wsyn[idx];
        wer[i] = w_[i] * erev[idx];
    }
    // Launder provenance: compiler can no longer rematerialize these from the
    // global loads above, so they must stay in VGPRs (R5 had VGPR=56 -> params
    // were re-loaded from global inside the serial loop, ~1000 cyc/step).
#pragma unroll
    for (int i = 0; i < 16; i++) {
        asm volatile("" : "+v"(sA[i]), "+v"(sB[i]), "+v"(wer[i]), "+v"(w_[i]));
    }
    float cmt = cm[u] * (float)UNFOLDS;
    float gl = gleak[u];
    float glvl = gl * vleak[u];
    float ow = outw[0], ob = outb[0];
    float v = 0.0f;
    int par = 0;

    float num_s = wns[(0 * BB + b) * UU + u];
    float den_s = wds[(0 * BB + b) * UU + u];
    for (int t = 0; t < TT; t++) {
        // prefetch next timestep's sensory sums (off critical path)
        float nns = 0.f, nds = 0.f;
        if (t + 1 < TT) {
            nns = wns[((t + 1) * BB + b) * UU + u];
            nds = wds[((t + 1) * BB + b) * UU + u];
        }
#pragma unroll
        for (int k = 0; k < UNFOLDS; k++) {
            float num = 0.0f, den = 0.0f;
#pragma unroll
            for (int i = 0; i < 16; i++) {
                float vi = bcast_lane(v, pc * 16 + i);
                float e = exp2f(fmaf(vi, sA[i], sB[i]));
                float r = __builtin_amdgcn_rcpf(1.0f + e);
                num = fmaf(wer[i], r, num);
                den = fmaf(w_[i], r, den);
            }
            pbuf[par][pc][u] = make_float2(num, den);
            __syncthreads();
            float2 p0 = pbuf[par][0][u];
            float2 p1 = pbuf[par][1][u];
            float2 p2 = pbuf[par][2][u];
            float2 p3 = pbuf[par][3][u];
            float nn = p0.x + p1.x + p2.x + p3.x + num_s;
            float dd = p0.y + p1.y + p2.y + p3.y + den_s;
            float denom = cmt + gl + dd + 1e-8f;
            v = (fmaf(cmt, v, glvl) + nn) * __builtin_amdgcn_rcpf(denom);
            par ^= 1;
        }
        if (pc == 0) {
            dout[384 + (b * TT + t) * UU + u] = v;
            if (u == 0) dout[b * TT + t] = fmaf(v, ow, ob);
            if (t == TT - 1) dout[128 + b * UU + u] = v;
        }
        num_s = nns;
        den_s = nds;
    }
}

extern "C" void kernel_launch(void* const* d_in, const int* in_sizes, int n_in,
                              void* d_out, int out_size, void* d_ws, size_t ws_size,
                              hipStream_t stream) {
    const float* in_seq = (const float*)d_in[0];
    const float* speed = (const float*)d_in[1];
    const float* c1w = (const float*)d_in[2];
    const float* c1b = (const float*)d_in[3];
    const float* c2w = (const float*)d_in[4];
    const float* c2b = (const float*)d_in[5];
    const float* c3w = (const float*)d_in[6];
    const float* c3b = (const float*)d_in[7];
    const float* hw = (const float*)d_in[8];
    const float* hb = (const float*)d_in[9];
    const float* sew1 = (const float*)d_in[10];
    const float* seb1 = (const float*)d_in[11];
    const float* sew2 = (const float*)d_in[12];
    const float* seb2 = (const float*)d_in[13];
    const float* inw = (const float*)d_in[14];
    const float* inb = (const float*)d_in[15];
    const float* gleak = (const float*)d_in[16];
    const float* vleak = (const float*)d_in[17];
    const float* cm = (const float*)d_in[18];
    const float* sigma = (const float*)d_in[19];
    const float* mu = (const float*)d_in[20];
    const float* wsyn = (const float*)d_in[21];
    const float* erev = (const float*)d_in[22];
    const float* ssig = (const float*)d_in[23];
    const float* smu = (const float*)d_in[24];
    const float* sw = (const float*)d_in[25];
    const float* serev = (const float*)d_in[26];
    const float* outw = (const float*)d_in[27];
    const float* outb = (const float*)d_in[28];

    char* ws = (char*)d_ws;
    float* out = (float*)d_out;

    size_t off = 0;
    auto alloc = [&](size_t bytes) {
        size_t o = off;
        off += (bytes + 255) & ~(size_t)255;
        return o;
    };
    ushort* inp1 = (ushort*)(ws + alloc((size_t)128 * 164 * 328 * 4 * 2));
    ushort* c1out = (ushort*)(ws + alloc((size_t)128 * 84 * 164 * 16 * 2));
    ushort* c2out = (ushort*)(ws + alloc((size_t)128 * 44 * 84 * 32 * 2));
    float* c3out = (float*)(ws + alloc((size_t)128 * 800 * 8 * 4));
    float* feats = (float*)(ws + alloc(8192 * 4));
    float* emb = (float*)(ws + alloc(1024 * 4));
    float* invstd = (float*)(ws + alloc(64));
    float* wns = (float*)(ws + alloc(8192 * 4));
    float* wds = (float*)(ws + alloc(8192 * 4));
    uint4* wz1 = (uint4*)(ws + alloc(5 * 64 * 16));
    uint4* wz2 = (uint4*)(ws + alloc(30 * 64 * 16));
    uint4* wz3 = (uint4*)(ws + alloc(25 * 64 * 16));

    // weight swizzles
    wswz1_kernel<<<5, 64, 0, stream>>>(c1w, wz1);
    wswz2_kernel<<<30, 64, 0, stream>>>(c2w, wz2);
    wswz3_kernel<<<25, 64, 0, stream>>>(c3w, wz3);

    // halo fills (halo-only grids) + input conversion
    fill_halo<164, 328, 160, 320, 4><<<1296, 256, 0, stream>>>(inp1);
    fill_halo<84, 164, 80, 160, 16><<<488, 256, 0, stream>>>(c1out);
    fill_halo<44, 84, 40, 80, 32><<<248, 256, 0, stream>>>(c2out);
    cvt_input<<<25600, 256, 0, stream>>>(in_seq, inp1);

    // MFMA convs
    conv1_mfma<<<6400, 256, 0, stream>>>(inp1, wz1, c1b, c1out);
    conv2_mfma<<<1600, 256, 0, stream>>>(c1out, wz2, c2b, c2out);
    conv3_mfma<<<400, 256, 0, stream>>>(c2out, wz3, c3b, c3out);

    // head + stats + speed embedding
    head_kernel<<<128, 256, 0, stream>>>(c3out, hw, hb, feats);
    stats_kernel<<<1, 256, 0, stream>>>(feats, invstd);
    semb_kernel<<<1, 128, 0, stream>>>(speed, sew1, seb1, sew2, seb2, emb);

    // sensory precompute
    sensory_kernel<<<TT * BB, 64, 0, stream>>>(feats, emb, invstd, inw, inb, ssig, smu, sw,
                                               serev, wns, wds);

    // serial LTC scan
    scan_kernel<<<BB, 256, 0, stream>>>(wns, wds, gleak, vleak, cm, sigma, mu, wsyn, erev,
                                        outw, outb, out);
}

// Round 7
// 277.237 us; speedup vs baseline: 3.6051x; 1.0068x over previous
//
#include <hip/hip_runtime.h>
#include <math.h>

// Problem constants
#define BB 4
#define TT 32
#define NF 8
#define FPF 8
#define SDIM 8
#define UU 64
#define SS 72
#define UNFOLDS 6

typedef short short8 __attribute__((ext_vector_type(8)));
typedef float f32x4 __attribute__((ext_vector_type(4)));
union Frag { uint4 u; short8 s; };

__device__ __forceinline__ float fast_sigmoid(float x) {
    float e = exp2f(-1.44269504f * x);
    return __builtin_amdgcn_rcpf(1.0f + e);
}

// fp32 -> bf16 bits, round-to-nearest-even (inputs finite)
__device__ __forceinline__ ushort f2b(float f) {
    union { float f; uint u; } a;
    a.f = f;
    uint u = a.u;
    return (ushort)((u + 0x7FFFu + ((u >> 16) & 1u)) >> 16);
}

__device__ __forceinline__ float bcast_lane(float v, int lane) {
    return __uint_as_float(__builtin_amdgcn_readlane(__float_as_uint(v), lane));
}

// ============ input f32 NCHW -> padded NHWC bf16 [128][164][328][4] (c3=0) ============
__global__ __launch_bounds__(256) void cvt_input(const float* __restrict__ in,
                                                 ushort* __restrict__ outp) {
    int idx = blockIdx.x * 256 + threadIdx.x;
    if (idx >= 128 * 160 * 320) return;
    int x = idx % 320;
    int r = idx / 320;
    int y = r % 160;
    int n = r / 160;
    const float* base = in + ((size_t)n * 3 * 160 + y) * 320 + x;
    float c0 = base[0];
    float c1 = base[160 * 320];
    float c2 = base[2 * 160 * 320];
    uint2 pk;
    pk.x = (uint)f2b(c0) | ((uint)f2b(c1) << 16);
    pk.y = (uint)f2b(c2);
    *(uint2*)(outp + ((size_t)((n * 164 + y + 2) * 328) + (x + 2)) * 4) = pk;
}

// ============ halo zero fill (halo-cells-only enumeration), merged ============
template <int HP, int WP, int H, int W, int CH>
__device__ __forceinline__ void halo_body(ushort* __restrict__ buf, int bid) {
    constexpr int TOPBOT = 2 * WP;
    constexpr int SIDE = WP - W;
    constexpr int NH = 2 * TOPBOT + H * SIDE;
    int idx = bid * 256 + threadIdx.x;
    if (idx >= 128 * NH) return;
    int n = idx / NH;
    int h = idx - n * NH;
    int y, x;
    if (h < TOPBOT) {
        y = h / WP;
        x = h % WP;
    } else if (h < 2 * TOPBOT) {
        int hh = h - TOPBOT;
        y = H + 2 + hh / WP;
        x = hh % WP;
    } else {
        int hh = h - 2 * TOPBOT;
        y = 2 + hh / SIDE;
        int xi = hh % SIDE;
        x = (xi < 2) ? xi : (W + xi);
    }
    ushort* p = buf + (((size_t)n * HP + y) * WP + x) * CH;
    if constexpr (CH == 4) {
        *(uint2*)p = make_uint2(0u, 0u);
    } else {
        uint4 z = make_uint4(0u, 0u, 0u, 0u);
#pragma unroll
        for (int i = 0; i < CH / 8; i++) *(uint4*)(p + i * 8) = z;
    }
}
// grids: halo1=1296, halo2=488, halo3=248 blocks -> 2032 total
__global__ __launch_bounds__(256) void fill_halo_all(ushort* __restrict__ p1,
                                                     ushort* __restrict__ p2,
                                                     ushort* __restrict__ p3) {
    int bid = blockIdx.x;
    if (bid < 1296)
        halo_body<164, 328, 160, 320, 4>(p1, bid);
    else if (bid < 1296 + 488)
        halo_body<84, 164, 80, 160, 16>(p2, bid - 1296);
    else
        halo_body<44, 84, 40, 80, 32>(p3, bid - 1784);
}

// ============ weight swizzles into MFMA A-fragment layout ============
__global__ void wswz1_kernel(const float* __restrict__ w, uint4* __restrict__ o) {
    int i = blockIdx.x * 64 + threadIdx.x;  // [5 ky][64 lanes]
    if (i >= 5 * 64) return;
    int lane = i & 63, s = i >> 6;
    int oc = lane & 15, q = lane >> 4;
    ushort v[8];
#pragma unroll
    for (int j = 0; j < 8; j++) {
        int k = q * 8 + j;
        int kx = k >> 2, c = k & 3;
        float f = (kx < 5 && c < 3) ? w[((oc * 3 + c) * 5 + s) * 5 + kx] : 0.f;
        v[j] = f2b(f);
    }
    uint4 u;
    u.x = (uint)v[0] | ((uint)v[1] << 16);
    u.y = (uint)v[2] | ((uint)v[3] << 16);
    u.z = (uint)v[4] | ((uint)v[5] << 16);
    u.w = (uint)v[6] | ((uint)v[7] << 16);
    o[i] = u;
}
__global__ void wswz2_kernel(const float* __restrict__ w, uint4* __restrict__ o) {
    int i = blockIdx.x * 64 + threadIdx.x;  // [15 kstep][2 octile][64]
    if (i >= 15 * 2 * 64) return;
    int lane = i & 63;
    int ct = (i >> 6) & 1;
    int s = i >> 7;
    int ky = s / 3, kxp = s % 3;
    int oc = ct * 16 + (lane & 15);
    int q = lane >> 4, h = q >> 1;
    int kx = 2 * kxp + h;
    ushort v[8];
#pragma unroll
    for (int j = 0; j < 8; j++) {
        int ch = (q & 1) * 8 + j;
        float f = (kx < 5) ? w[((oc * 16 + ch) * 5 + ky) * 5 + kx] : 0.f;
        v[j] = f2b(f);
    }
    uint4 u;
    u.x = (uint)v[0] | ((uint)v[1] << 16);
    u.y = (uint)v[2] | ((uint)v[3] << 16);
    u.z = (uint)v[4] | ((uint)v[5] << 16);
    u.w = (uint)v[6] | ((uint)v[7] << 16);
    o[i] = u;
}
__global__ void wswz3_kernel(const float* __restrict__ w, uint4* __restrict__ o) {
    int i = blockIdx.x * 64 + threadIdx.x;  // [25 tap][64]
    if (i >= 25 * 64) return;
    int lane = i & 63, s = i >> 6;
    int ky = s / 5, kx = s % 5;
    int oc = lane & 15, q = lane >> 4;
    ushort v[8];
#pragma unroll
    for (int j = 0; j < 8; j++) {
        int ch = q * 8 + j;
        float f = (oc < 8) ? w[((oc * 32 + ch) * 5 + ky) * 5 + kx] : 0.f;
        v[j] = f2b(f);
    }
    uint4 u;
    u.x = (uint)v[0] | ((uint)v[1] << 16);
    u.y = (uint)v[2] | ((uint)v[3] << 16);
    u.z = (uint)v[4] | ((uint)v[5] << 16);
    u.w = (uint)v[6] | ((uint)v[7] << 16);
    o[i] = u;
}

// ============ conv1: [128][164][328][4] -> [128][84][164][16], 5 ksteps (ky) ============
__global__ __launch_bounds__(256) void conv1_mfma(const ushort* __restrict__ inp,
                                                  const uint4* __restrict__ wswz,
                                                  const float* __restrict__ bias,
                                                  ushort* __restrict__ outp) {
    const int lane = threadIdx.x & 63;
    const int wid = threadIdx.x >> 6;
    const int col = lane & 15, q = lane >> 4;

    Frag A[5];
#pragma unroll
    for (int s = 0; s < 5; s++) A[s].u = wswz[s * 64 + lane];
    float b0 = bias[q * 4 + 0], b1 = bias[q * 4 + 1], b2 = bias[q * 4 + 2], b3 = bias[q * 4 + 3];

    int gw = blockIdx.x * 4 + wid;
#pragma unroll
    for (int t = 0; t < 4; t++) {
        int p0 = gw * 64 + t * 16;
        int n = p0 / 12800;
        int rem = p0 - n * 12800;
        int oy = rem / 160;
        int ox0 = rem - oy * 160;
        int ox = ox0 + col;
        uint e0 = ((uint)(n * 164 + oy * 2) * 328u + (uint)(ox * 2 + 2 * q)) * 4u;
        f32x4 acc = {0.f, 0.f, 0.f, 0.f};
#pragma unroll
        for (int s = 0; s < 5; s++) {
            Frag B;
            B.u = *(const uint4*)(inp + e0 + (uint)s * (328u * 4u));
            acc = __builtin_amdgcn_mfma_f32_16x16x32_bf16(A[s].s, B.s, acc, 0, 0, 0);
        }
        uint oe = ((uint)(n * 84 + oy + 2) * 164u + (uint)(ox + 2)) * 16u + q * 4u;
        uint2 pk;
        pk.x = (uint)f2b(fmaxf(acc[0] + b0, 0.f)) | ((uint)f2b(fmaxf(acc[1] + b1, 0.f)) << 16);
        pk.y = (uint)f2b(fmaxf(acc[2] + b2, 0.f)) | ((uint)f2b(fmaxf(acc[3] + b3, 0.f)) << 16);
        *(uint2*)(outp + oe) = pk;
    }
}

// ============ conv2: [128][84][164][16] -> [128][44][84][32], 15 ksteps ============
__global__ __launch_bounds__(256) void conv2_mfma(const ushort* __restrict__ inp,
                                                  const uint4* __restrict__ wswz,
                                                  const float* __restrict__ bias,
                                                  ushort* __restrict__ outp) {
    const int lane = threadIdx.x & 63;
    const int wid = threadIdx.x >> 6;
    const int col = lane & 15, q = lane >> 4;
    const int h = q >> 1, chh = q & 1;

    int gw = blockIdx.x * 4 + wid;
    uint eb[4];
#pragma unroll
    for (int t = 0; t < 4; t++) {
        int p0 = gw * 64 + t * 16;
        int n = p0 / 3200;
        int rem = p0 - n * 3200;
        int oy = rem / 80;
        int ox0 = rem - oy * 80;
        eb[t] = ((uint)(n * 84 + oy * 2) * 164u + (uint)((ox0 + col) * 2 + h)) * 16u + chh * 8u;
    }
    f32x4 acc[4][2];
#pragma unroll
    for (int t = 0; t < 4; t++) {
        acc[t][0] = {0.f, 0.f, 0.f, 0.f};
        acc[t][1] = {0.f, 0.f, 0.f, 0.f};
    }
#pragma unroll
    for (int s = 0; s < 15; s++) {
        const int ky = s / 3, kxp = s % 3;
        Frag A0, A1;
        A0.u = wswz[(s * 2 + 0) * 64 + lane];
        A1.u = wswz[(s * 2 + 1) * 64 + lane];
        const uint d = (uint)ky * (164u * 16u) + (uint)kxp * 32u;
#pragma unroll
        for (int t = 0; t < 4; t++) {
            Frag B;
            B.u = *(const uint4*)(inp + eb[t] + d);
            acc[t][0] = __builtin_amdgcn_mfma_f32_16x16x32_bf16(A0.s, B.s, acc[t][0], 0, 0, 0);
            acc[t][1] = __builtin_amdgcn_mfma_f32_16x16x32_bf16(A1.s, B.s, acc[t][1], 0, 0, 0);
        }
    }
    float ba[2][4];
#pragma unroll
    for (int c = 0; c < 2; c++)
#pragma unroll
        for (int r = 0; r < 4; r++) ba[c][r] = bias[c * 16 + q * 4 + r];
#pragma unroll
    for (int t = 0; t < 4; t++) {
        int p0 = gw * 64 + t * 16;
        int n = p0 / 3200;
        int rem = p0 - n * 3200;
        int oy = rem / 80;
        int ox0 = rem - oy * 80;
        int ox = ox0 + col;
        uint oe = ((uint)(n * 44 + oy + 2) * 84u + (uint)(ox + 2)) * 32u;
#pragma unroll
        for (int c = 0; c < 2; c++) {
            uint2 pk;
            pk.x = (uint)f2b(fmaxf(acc[t][c][0] + ba[c][0], 0.f)) |
                   ((uint)f2b(fmaxf(acc[t][c][1] + ba[c][1], 0.f)) << 16);
            pk.y = (uint)f2b(fmaxf(acc[t][c][2] + ba[c][2], 0.f)) |
                   ((uint)f2b(fmaxf(acc[t][c][3] + ba[c][3], 0.f)) << 16);
            *(uint2*)(outp + oe + (uint)c * 16u + (uint)q * 4u) = pk;
        }
    }
}

// ============ conv3: [128][44][84][32] -> [128][800][8] f32 (NHWC), 25 ksteps ============
__global__ __launch_bounds__(256) void conv3_mfma(const ushort* __restrict__ inp,
                                                  const uint4* __restrict__ wswz,
                                                  const float* __restrict__ bias,
                                                  float* __restrict__ outp) {
    const int lane = threadIdx.x & 63;
    const int wid = threadIdx.x >> 6;
    const int col = lane & 15, q = lane >> 4;

    int gw = blockIdx.x * 4 + wid;
    uint eb[4];
#pragma unroll
    for (int t = 0; t < 4; t++) {
        int p0 = gw * 64 + t * 16;
        int n = p0 / 800;
        int pix = p0 - n * 800 + col;  // per-lane coords (row-wrap safe, OW=40)
        int oy = pix / 40;
        int ox = pix - oy * 40;
        eb[t] = ((uint)(n * 44 + oy * 2) * 84u + (uint)(ox * 2)) * 32u + q * 8u;
    }
    f32x4 acc[4];
#pragma unroll
    for (int t = 0; t < 4; t++) acc[t] = {0.f, 0.f, 0.f, 0.f};
#pragma unroll
    for (int s = 0; s < 25; s++) {
        const int ky = s / 5, kx = s % 5;
        Frag A;
        A.u = wswz[s * 64 + lane];
        const uint d = ((uint)ky * 84u + (uint)kx) * 32u;
#pragma unroll
        for (int t = 0; t < 4; t++) {
            Frag B;
            B.u = *(const uint4*)(inp + eb[t] + d);
            acc[t] = __builtin_amdgcn_mfma_f32_16x16x32_bf16(A.s, B.s, acc[t], 0, 0, 0);
        }
    }
    if (q < 2) {
        float b0 = bias[q * 4 + 0], b1 = bias[q * 4 + 1];
        float b2 = bias[q * 4 + 2], b3 = bias[q * 4 + 3];
#pragma unroll
        for (int t = 0; t < 4; t++) {
            int p0 = gw * 64 + t * 16;
            int n = p0 / 800;
            int p = p0 - n * 800 + col;
            float4 v;
            v.x = fmaxf(acc[t][0] + b0, 0.f);
            v.y = fmaxf(acc[t][1] + b1, 0.f);
            v.z = fmaxf(acc[t][2] + b2, 0.f);
            v.w = fmaxf(acc[t][3] + b3, 0.f);
            *(float4*)(outp + ((size_t)n * 800 + p) * 8 + q * 4) = v;
        }
    }
}

// ============ head: 256 threads, 4-way p-split + LDS reduce ============
__global__ __launch_bounds__(256) void head_kernel(const float* __restrict__ x,
                                                   const float* __restrict__ hw,
                                                   const float* __restrict__ hb,
                                                   float* __restrict__ feats) {
    __shared__ float part[4][64];
    int n = blockIdx.x;
    int tid = threadIdx.x;
    int lane = tid & 63;
    int c = tid >> 6;  // p-chunk 0..3
    int f = lane >> 3;
    int k = lane & 7;
    const float* xb = x + (size_t)n * 800 * 8 + f;
    const float* wb = hw + ((size_t)f * 800) * FPF + k;
    float acc = 0.0f;
    for (int p = c * 200; p < c * 200 + 200; p++)
        acc = fmaf(xb[(size_t)p * 8], wb[(size_t)p * FPF], acc);
    part[c][lane] = acc;
    __syncthreads();
    if (c == 0)
        feats[n * 64 + lane] = part[0][lane] + part[1][lane] + part[2][lane] + part[3][lane] +
                               hb[lane];
}

// ============ global std (ddof=1) ============
__global__ void stats_kernel(const float* __restrict__ feats, float* __restrict__ invstd) {
    __shared__ float s_sum[256], s_sq[256];
    int tid = threadIdx.x;
    float s = 0.0f, q = 0.0f;
    for (int i = tid; i < 8192; i += 256) {
        float x = feats[i];
        s += x;
        q += x * x;
    }
    s_sum[tid] = s;
    s_sq[tid] = q;
    __syncthreads();
    for (int off = 128; off > 0; off >>= 1) {
        if (tid < off) {
            s_sum[tid] += s_sum[tid + off];
            s_sq[tid] += s_sq[tid + off];
        }
        __syncthreads();
    }
    if (tid == 0) {
        float mean = s_sum[0] / 8192.0f;
        float var = (s_sq[0] - 8192.0f * mean * mean) / 8191.0f;
        var = fmaxf(var, 0.0f);
        invstd[0] = 1.0f / (sqrtf(var) + 1e-5f);
    }
}

// ============ speed embedding ============
__global__ void semb_kernel(const float* __restrict__ speed, const float* __restrict__ w1,
                            const float* __restrict__ b1, const float* __restrict__ w2,
                            const float* __restrict__ b2, float* __restrict__ emb) {
    int n = threadIdx.x;  // 0..127
    float s = speed[n];
    float h[16];
#pragma unroll
    for (int j = 0; j < 16; j++) h[j] = fmaxf(fmaf(s, w1[j], b1[j]), 0.0f);
#pragma unroll
    for (int k = 0; k < SDIM; k++) {
        float a = b2[k];
#pragma unroll
        for (int j = 0; j < 16; j++) a = fmaf(h[j], w2[j * SDIM + k], a);
        emb[n * SDIM + k] = tanhf(a);
    }
}

// ============ sensory precompute ============
__global__ void sensory_kernel(const float* __restrict__ feats, const float* __restrict__ emb,
                               const float* __restrict__ invstd, const float* __restrict__ inw,
                               const float* __restrict__ inb, const float* __restrict__ ssig,
                               const float* __restrict__ smu, const float* __restrict__ sw,
                               const float* __restrict__ serev, float* __restrict__ wns,
                               float* __restrict__ wds) {
    int bid = blockIdx.x;  // t*4 + b
    int t = bid >> 2;
    int b = bid & 3;
    int u = threadIdx.x;  // 0..63
    int n = b * TT + t;
    float inv = invstd[0];
    float num = 0.0f, den = 0.0f;
    for (int s = 0; s < SS; s++) {
        float xsv = (s < 64) ? feats[n * 64 + s] * inv : emb[n * SDIM + (s - 64)];
        float inp = fmaf(xsv, inw[s], inb[s]);
        int idx = s * UU + u;
        float x = (inp - smu[idx]) * ssig[idx];
        float act = sw[idx] * fast_sigmoid(x);
        num = fmaf(act, serev[idx], num);
        den += act;
    }
    wns[bid * UU + u] = num;
    wds[bid * UU + u] = den;
}

// ============ LTC scan v4: 8 waves, lgkm-only barrier, SGPR lane index ============
// 4 blocks (one per batch), 512 threads = 8 waves x 8 pre-synapses per lane.
// __syncthreads would drain vmcnt(0) at every barrier (prefetch loads + dout
// stores on the critical path) -> use raw s_barrier with lgkmcnt-only wait.
__global__ __launch_bounds__(512, 1) void scan_kernel(
    const float* __restrict__ wns, const float* __restrict__ wds,
    const float* __restrict__ gleak, const float* __restrict__ vleak,
    const float* __restrict__ cm, const float* __restrict__ sigma,
    const float* __restrict__ mu, const float* __restrict__ wsyn,
    const float* __restrict__ erev, const float* __restrict__ outw,
    const float* __restrict__ outb, float* __restrict__ dout) {
    int b = blockIdx.x;
    int tid = threadIdx.x;
    int u = tid & 63;
    // wave index pinned to SGPR so readlane gets a scalar lane operand
    int pc_s = __builtin_amdgcn_readfirstlane(tid >> 6);  // 0..7

    __shared__ float2 pbuf[2][8][64];

    // strength-reduced synapse params: arg = fma(v, sA, sB); act = w * sigmoid
    float sA[8], sB[8], wer[8], w_[8];
#pragma unroll
    for (int i = 0; i < 8; i++) {
        int idx = (pc_s * 8 + i) * UU + u;
        float sg = sigma[idx];
        sA[i] = -1.44269504f * sg;
        sB[i] = -sA[i] * mu[idx];
        w_[i] = wsyn[idx];
        wer[i] = w_[i] * erev[idx];
    }
#pragma unroll
    for (int i = 0; i < 8; i++) {
        asm volatile("" : "+v"(sA[i]), "+v"(sB[i]), "+v"(wer[i]), "+v"(w_[i]));
    }
    float cmt = cm[u] * (float)UNFOLDS;
    float gl = gleak[u];
    float glvl = gl * vleak[u];
    float ow = outw[0], ob = outb[0];
    float v = 0.0f;
    int par = 0;

    float num_s = wns[(0 * BB + b) * UU + u];
    float den_s = wds[(0 * BB + b) * UU + u];
    for (int t = 0; t < TT; t++) {
        // prefetch next timestep's sensory sums (no vmcnt drain at barriers now)
        float nns = 0.f, nds = 0.f;
        if (t + 1 < TT) {
            nns = wns[((t + 1) * BB + b) * UU + u];
            nds = wds[((t + 1) * BB + b) * UU + u];
        }
#pragma unroll
        for (int k = 0; k < UNFOLDS; k++) {
            float num = 0.0f, den = 0.0f;
#pragma unroll
            for (int i = 0; i < 8; i++) {
                float vi = bcast_lane(v, pc_s * 8 + i);
                float e = exp2f(fmaf(vi, sA[i], sB[i]));
                float r = __builtin_amdgcn_rcpf(1.0f + e);
                num = fmaf(wer[i], r, num);
                den = fmaf(w_[i], r, den);
            }
            pbuf[par][pc_s][u] = make_float2(num, den);
            // LDS-only barrier: wait LDS write visibility, sync, fence reads after
            __builtin_amdgcn_sched_barrier(0);
            asm volatile("s_waitcnt lgkmcnt(0)" ::: "memory");
            __builtin_amdgcn_s_barrier();
            asm volatile("" ::: "memory");
            __builtin_amdgcn_sched_barrier(0);
            float nn = num_s, dd = den_s;
#pragma unroll
            for (int j = 0; j < 8; j++) {
                float2 p = pbuf[par][j][u];
                nn += p.x;
                dd += p.y;
            }
            float denom = cmt + gl + dd + 1e-8f;
            v = (fmaf(cmt, v, glvl) + nn) * __builtin_amdgcn_rcpf(denom);
            par ^= 1;
        }
        if (pc_s == 0) {
            dout[384 + (b * TT + t) * UU + u] = v;
            if (u == 0) dout[b * TT + t] = fmaf(v, ow, ob);
            if (t == TT - 1) dout[128 + b * UU + u] = v;
        }
        num_s = nns;
        den_s = nds;
    }
}

extern "C" void kernel_launch(void* const* d_in, const int* in_sizes, int n_in,
                              void* d_out, int out_size, void* d_ws, size_t ws_size,
                              hipStream_t stream) {
    const float* in_seq = (const float*)d_in[0];
    const float* speed = (const float*)d_in[1];
    const float* c1w = (const float*)d_in[2];
    const float* c1b = (const float*)d_in[3];
    const float* c2w = (const float*)d_in[4];
    const float* c2b = (const float*)d_in[5];
    const float* c3w = (const float*)d_in[6];
    const float* c3b = (const float*)d_in[7];
    const float* hw = (const float*)d_in[8];
    const float* hb = (const float*)d_in[9];
    const float* sew1 = (const float*)d_in[10];
    const float* seb1 = (const float*)d_in[11];
    const float* sew2 = (const float*)d_in[12];
    const float* seb2 = (const float*)d_in[13];
    const float* inw = (const float*)d_in[14];
    const float* inb = (const float*)d_in[15];
    const float* gleak = (const float*)d_in[16];
    const float* vleak = (const float*)d_in[17];
    const float* cm = (const float*)d_in[18];
    const float* sigma = (const float*)d_in[19];
    const float* mu = (const float*)d_in[20];
    const float* wsyn = (const float*)d_in[21];
    const float* erev = (const float*)d_in[22];
    const float* ssig = (const float*)d_in[23];
    const float* smu = (const float*)d_in[24];
    const float* sw = (const float*)d_in[25];
    const float* serev = (const float*)d_in[26];
    const float* outw = (const float*)d_in[27];
    const float* outb = (const float*)d_in[28];

    char* ws = (char*)d_ws;
    float* out = (float*)d_out;

    size_t off = 0;
    auto alloc = [&](size_t bytes) {
        size_t o = off;
        off += (bytes + 255) & ~(size_t)255;
        return o;
    };
    ushort* inp1 = (ushort*)(ws + alloc((size_t)128 * 164 * 328 * 4 * 2));
    ushort* c1out = (ushort*)(ws + alloc((size_t)128 * 84 * 164 * 16 * 2));
    ushort* c2out = (ushort*)(ws + alloc((size_t)128 * 44 * 84 * 32 * 2));
    float* c3out = (float*)(ws + alloc((size_t)128 * 800 * 8 * 4));
    float* feats = (float*)(ws + alloc(8192 * 4));
    float* emb = (float*)(ws + alloc(1024 * 4));
    float* invstd = (float*)(ws + alloc(64));
    float* wns = (float*)(ws + alloc(8192 * 4));
    float* wds = (float*)(ws + alloc(8192 * 4));
    uint4* wz1 = (uint4*)(ws + alloc(5 * 64 * 16));
    uint4* wz2 = (uint4*)(ws + alloc(30 * 64 * 16));
    uint4* wz3 = (uint4*)(ws + alloc(25 * 64 * 16));

    // weight swizzles
    wswz1_kernel<<<5, 64, 0, stream>>>(c1w, wz1);
    wswz2_kernel<<<30, 64, 0, stream>>>(c2w, wz2);
    wswz3_kernel<<<25, 64, 0, stream>>>(c3w, wz3);

    // halo fills (merged, halo-only grids) + input conversion
    fill_halo_all<<<2032, 256, 0, stream>>>(inp1, c1out, c2out);
    cvt_input<<<25600, 256, 0, stream>>>(in_seq, inp1);

    // MFMA convs
    conv1_mfma<<<6400, 256, 0, stream>>>(inp1, wz1, c1b, c1out);
    conv2_mfma<<<1600, 256, 0, stream>>>(c1out, wz2, c2b, c2out);
    conv3_mfma<<<400, 256, 0, stream>>>(c2out, wz3, c3b, c3out);

    // head + stats + speed embedding
    head_kernel<<<128, 256, 0, stream>>>(c3out, hw, hb, feats);
    stats_kernel<<<1, 256, 0, stream>>>(feats, invstd);
    semb_kernel<<<1, 128, 0, stream>>>(speed, sew1, seb1, sew2, seb2, emb);

    // sensory precompute
    sensory_kernel<<<TT * BB, 64, 0, stream>>>(feats, emb, invstd, inw, inb, ssig, smu, sw,
                                               serev, wns, wds);

    // serial LTC scan
    scan_kernel<<<BB, 512, 0, stream>>>(wns, wds, gleak, vleak, cm, sigma, mu, wsyn, erev,
                                        outw, outb, out);
}